// Round 3
// baseline (1185.520 us; speedup 1.0000x reference)
//
#include <hip/hip_runtime.h>
#include <hip/hip_bf16.h>

// SymbolicGNN: 2-layer edge-MLP message passing + scatter-add + mean-pool + linear head.
// fp32 accumulator A in d_ws + bf16 mirror hb for gathers (rebuilt between layers).
// Edge kernel: 32-edge tile/block, 4 waves, bf16 MFMA, register-prefetch pipeline:
// next tile's gather rows are loaded into regs while current tile computes; barriers
// are lgkmcnt-only (inline asm) so prefetch loads stay in flight across them.

#define N_NODES 100000
#define NV_ELEMS (N_NODES * 64)
#define N_EDGES 1000000
#define ES 64
#define TILE 32
#define NTILES (N_EDGES / TILE)

typedef __bf16 bf16x8 __attribute__((ext_vector_type(8)));
typedef __bf16 bf16x4 __attribute__((ext_vector_type(4)));
typedef float f32x4 __attribute__((ext_vector_type(4)));

__device__ __forceinline__ f32x4 mfma_16x16x32(bf16x8 a, bf16x8 b, f32x4 c) {
    return __builtin_amdgcn_mfma_f32_16x16x32_bf16(a, b, c, 0, 0, 0);
}

// LDS-only barrier: drains ds ops for visibility but leaves global loads in flight.
// All cross-thread deps in k_edges are LDS (sX/sHm/sO); global buffers are either
// read-only or write-only-atomic within the kernel, so vmcnt need not drain.
#define BAR() asm volatile("s_waitcnt lgkmcnt(0)\n\ts_barrier" ::: "memory")

// GELU with Abramowitz-Stegun 7.1.26 erf (max abs err 1.5e-7 in erf).
__device__ __forceinline__ float gelu_fast(float v) {
    float u  = fabsf(v) * 0.70710678118654752f;
    float t  = __builtin_amdgcn_rcpf(fmaf(0.3275911f, u, 1.0f));
    float e  = __expf(-u * u);
    float p  = t * fmaf(t, fmaf(t, fmaf(t, fmaf(t, 1.061405429f, -1.453152027f),
                                        1.421413741f), -0.284496736f), 0.254829592f);
    float er = fmaf(-p, e, 1.0f);
    float s  = (v >= 0.0f) ? er : -er;
    return 0.5f * v * (1.0f + s);
}

__global__ void k_init(const float* __restrict__ sym, float* __restrict__ A,
                       __bf16* __restrict__ hb, float* __restrict__ pooled) {
    const int total4 = NV_ELEMS / 4;
    const float4* s4 = (const float4*)sym;
    float4* a4 = (float4*)A;
    for (int i = blockIdx.x * blockDim.x + threadIdx.x; i < total4;
         i += gridDim.x * blockDim.x) {
        float4 v = s4[i];
        a4[i] = v;
        bf16x4 p;
        p[0] = (__bf16)v.x; p[1] = (__bf16)v.y; p[2] = (__bf16)v.z; p[3] = (__bf16)v.w;
        *(bf16x4*)(hb + (size_t)i * 4) = p;
    }
    if (blockIdx.x == 0 && threadIdx.x < ES) pooled[threadIdx.x] = 0.0f;
}

__global__ void k_h2b(const float* __restrict__ A, __bf16* __restrict__ hb) {
    const int total4 = NV_ELEMS / 4;
    const float4* a4 = (const float4*)A;
    for (int i = blockIdx.x * blockDim.x + threadIdx.x; i < total4;
         i += gridDim.x * blockDim.x) {
        float4 v = a4[i];
        bf16x4 p;
        p[0] = (__bf16)v.x; p[1] = (__bf16)v.y; p[2] = (__bf16)v.z; p[3] = (__bf16)v.w;
        *(bf16x4*)(hb + (size_t)i * 4) = p;
    }
}

// One block = one 32-edge tile (grid-stride), 4 waves.
__global__ __launch_bounds__(256, 4) void k_edges(
    const int* __restrict__ subj, const int* __restrict__ pred, const int* __restrict__ obj,
    const __bf16* __restrict__ hb, float* __restrict__ A,
    const float* __restrict__ eemb,
    const float* __restrict__ w1, const float* __restrict__ b1,
    const float* __restrict__ w2, const float* __restrict__ b2) {
    __shared__ __bf16 sX[TILE][200];   // 12.8 KB, X = [h_subj | e | h_obj] bf16
    __shared__ __bf16 sHm[TILE][136];  // 8.7 KB, unified hmid
    __shared__ int    sO[TILE];

    const int tid = threadIdx.x;
    const int w   = tid >> 6;
    const int l   = tid & 63;
    const int lg  = l >> 4;
    const int lc  = l & 15;

    // ---- weight fragments in registers (amortized over grid-stride tiles) ----
    bf16x8 wb1[6][2];
#pragma unroll
    for (int kt = 0; kt < 6; ++kt)
#pragma unroll
        for (int nt = 0; nt < 2; ++nt) {
            bf16x8 f;
#pragma unroll
            for (int i = 0; i < 8; ++i) {
                int k   = kt * 32 + lg * 8 + i;
                int col = w * 32 + nt * 16 + lc;
                f[i] = (__bf16)w1[k * 128 + col];
            }
            wb1[kt][nt] = f;
        }
    bf16x8 wb2[4];
#pragma unroll
    for (int kt = 0; kt < 4; ++kt) {
        bf16x8 f;
#pragma unroll
        for (int i = 0; i < 8; ++i) {
            int k = kt * 32 + lg * 8 + i;
            f[i] = (__bf16)w2[k * 64 + w * 16 + lc];
        }
        wb2[kt] = f;
    }
    const float b1c0 = b1[w * 32 + lc];
    const float b1c1 = b1[w * 32 + 16 + lc];
    const int   scol = w * 16 + lc;
    const float b2v  = b2[scol];

    // ---- per-thread gather plan: 6 (row,part) segments, 16 lanes per segment ----
    const int g16 = tid >> 4, l16 = tid & 15;
    int rowA[6], partA[6];
#pragma unroll
    for (int it = 0; it < 6; ++it) {
        int seg = it * 16 + g16;
        rowA[it] = seg / 3;
        partA[it] = seg - 3 * rowA[it];
    }

#define PREFETCH_IDX(E0)                                                      \
    _Pragma("unroll") for (int it = 0; it < 6; ++it) {                        \
        const int* ip = partA[it] == 0 ? subj : (partA[it] == 1 ? pred : obj);\
        idx[it] = ip[(E0) + rowA[it]];                                        \
    }
    // parts 0/2: 8B bf16x4 from hb; part 1: 16B float4 from eemb (fp32 table)
#define PREFETCH_GATHER()                                                     \
    _Pragma("unroll") for (int it = 0; it < 6; ++it) {                        \
        if (partA[it] == 1)                                                   \
            rf[it] = *(const float4*)(eemb + (size_t)idx[it] * ES + l16 * 4); \
        else                                                                  \
            rb[it] = *(const bf16x4*)(hb + (size_t)idx[it] * ES + l16 * 4);   \
    }

    int    idx[6];
    bf16x4 rb[6];
    float4 rf[6];
    int    objn = 0;

    int tile = blockIdx.x;
    const int stride = gridDim.x;
    if (tile >= NTILES) return;

    // prologue: fetch first tile into regs
    PREFETCH_IDX(tile * TILE);
    if (tid < TILE) objn = obj[tile * TILE + tid];
    PREFETCH_GATHER();

    for (; tile < NTILES; tile += stride) {
        const int nxt = (tile + stride < NTILES) ? (tile + stride) : tile;
        const int en0 = nxt * TILE;

        // ---- stage current tile's X (regs -> LDS); issue next tile's index loads ----
#pragma unroll
        for (int it = 0; it < 6; ++it) {
            if (partA[it] == 1) {
                bf16x4 p;
                p[0] = (__bf16)rf[it].x; p[1] = (__bf16)rf[it].y;
                p[2] = (__bf16)rf[it].z; p[3] = (__bf16)rf[it].w;
                *(bf16x4*)&sX[rowA[it]][64 + l16 * 4] = p;
            } else {
                *(bf16x4*)&sX[rowA[it]][partA[it] * 64 + l16 * 4] = rb[it];
            }
        }
        if (tid < TILE) sO[tid] = objn;
        PREFETCH_IDX(en0);
        if (tid < TILE) objn = obj[en0 + tid];
        BAR();  // syncA: sX, sO visible

        // scatter targets to regs (so next iter's sO write can't race our reads)
        int objr[8];
#pragma unroll
        for (int mt = 0; mt < 2; ++mt)
#pragma unroll
            for (int r = 0; r < 4; ++r) objr[mt * 4 + r] = sO[mt * 16 + lg * 4 + r];

        // ---- GEMM1: (32x192) @ W1 -> this wave's 32x32 hmid slice ----
        f32x4 acc1[2][2];
#pragma unroll
        for (int mt = 0; mt < 2; ++mt)
#pragma unroll
            for (int nt = 0; nt < 2; ++nt) acc1[mt][nt] = (f32x4){0.f, 0.f, 0.f, 0.f};
#pragma unroll
        for (int kt = 0; kt < 6; ++kt) {
#pragma unroll
            for (int mt = 0; mt < 2; ++mt) {
                bf16x8 a = *(const bf16x8*)&sX[mt * 16 + lc][kt * 32 + lg * 8];
                acc1[mt][0] = mfma_16x16x32(a, wb1[kt][0], acc1[mt][0]);
                acc1[mt][1] = mfma_16x16x32(a, wb1[kt][1], acc1[mt][1]);
            }
        }

        // ---- issue next tile's gathers: latency hides under GELU + GEMM2 ----
        PREFETCH_GATHER();

        // ---- bias + GELU -> hmid LDS (C-layout: row=(l>>4)*4+r, col=l&15) ----
#pragma unroll
        for (int mt = 0; mt < 2; ++mt)
#pragma unroll
            for (int nt = 0; nt < 2; ++nt) {
                float bias = nt ? b1c1 : b1c0;
#pragma unroll
                for (int r = 0; r < 4; ++r) {
                    float g = gelu_fast(acc1[mt][nt][r] + bias);
                    sHm[mt * 16 + lg * 4 + r][w * 32 + nt * 16 + lc] = (__bf16)g;
                }
            }
        BAR();  // syncB: sHm visible

        // ---- GEMM2: hmid(32x128) @ W2[:, 16w:16w+16) -> msg cols ----
        f32x4 acc2[2];
        acc2[0] = (f32x4){0.f, 0.f, 0.f, 0.f};
        acc2[1] = (f32x4){0.f, 0.f, 0.f, 0.f};
#pragma unroll
        for (int kt = 0; kt < 4; ++kt) {
#pragma unroll
            for (int mt = 0; mt < 2; ++mt) {
                bf16x8 a = *(const bf16x8*)&sHm[mt * 16 + lc][kt * 32 + lg * 8];
                acc2[mt] = mfma_16x16x32(a, wb2[kt], acc2[mt]);
            }
        }

        // ---- + b2, scatter-add (device-scope atomics) ----
#pragma unroll
        for (int mt = 0; mt < 2; ++mt)
#pragma unroll
            for (int r = 0; r < 4; ++r)
                atomicAdd(&A[(size_t)objr[mt * 4 + r] * ES + scol], acc2[mt][r] + b2v);
    }
#undef PREFETCH_IDX
#undef PREFETCH_GATHER
}

__global__ void k_pool(const float* __restrict__ h, float* __restrict__ pooled) {
    __shared__ float sm[256];
    float acc = 0.f;
    for (int idx = blockIdx.x * 256 + threadIdx.x; idx < NV_ELEMS; idx += gridDim.x * 256)
        acc += h[idx];
    sm[threadIdx.x] = acc;
    __syncthreads();
    if (threadIdx.x < 64) {
        float s = sm[threadIdx.x] + sm[threadIdx.x + 64] + sm[threadIdx.x + 128] +
                  sm[threadIdx.x + 192];
        atomicAdd(&pooled[threadIdx.x], s);
    }
}

__global__ void k_final(const float* __restrict__ pooled, const float* __restrict__ w,
                        const float* __restrict__ b, float* __restrict__ out) {
    __shared__ float sp[64];
    if (threadIdx.x < 64) sp[threadIdx.x] = pooled[threadIdx.x] * (1.0f / N_NODES);
    __syncthreads();
    const int c = threadIdx.x;
    float s = b[c];
#pragma unroll
    for (int j = 0; j < 64; ++j) s += sp[j] * w[j * 256 + c];
    out[c] = s;
}

extern "C" void kernel_launch(void* const* d_in, const int* in_sizes, int n_in,
                              void* d_out, int out_size, void* d_ws, size_t ws_size,
                              hipStream_t stream) {
    const int*   subj = (const int*)d_in[0];
    const int*   pred = (const int*)d_in[1];
    const int*   obj  = (const int*)d_in[2];
    const float* sym  = (const float*)d_in[3];
    const float* eemb = (const float*)d_in[4];
    const float* w1   = (const float*)d_in[5];
    const float* b1   = (const float*)d_in[6];
    const float* w2   = (const float*)d_in[7];
    const float* b2   = (const float*)d_in[8];
    const float* lw   = (const float*)d_in[9];
    const float* lb   = (const float*)d_in[10];
    float* out = (float*)d_out;

    float*  A      = (float*)d_ws;                       // fp32 h accumulator, 25.6 MB
    __bf16* hb     = (__bf16*)(A + (size_t)NV_ELEMS);    // bf16 gather mirror, 12.8 MB
    float*  pooled = (float*)(hb + (size_t)NV_ELEMS);    // 64 floats

    // A = sym[0:N] (node ids 0..N-1 < VOCAB), hb = bf16(A), pooled = 0
    k_init<<<2048, 256, 0, stream>>>(sym, A, hb, pooled);
    // layer 0: gather hb, scatter into A (A pre-initialized to h0)
    k_edges<<<2048, 256, 0, stream>>>(subj, pred, obj, hb, A, eemb, w1, b1, w2, b2);
    // refresh bf16 mirror from accumulated h
    k_h2b<<<2048, 256, 0, stream>>>(A, hb);
    // layer 1: gather hb (= bf16 of current h), scatter in-place into A
    k_edges<<<2048, 256, 0, stream>>>(subj, pred, obj, hb, A, eemb,
                                      w1 + 192 * 128, b1 + 128, w2 + 128 * 64, b2 + 64);
    // mean-pool columns of A, then linear head
    k_pool<<<256, 256, 0, stream>>>(A, pooled);
    k_final<<<1, 256, 0, stream>>>(pooled, lw, lb, out);
}

// Round 4
// 948.119 us; speedup vs baseline: 1.2504x; 1.2504x over previous
//
#include <hip/hip_runtime.h>
#include <hip/hip_bf16.h>

// SymbolicGNN, CSR two-phase edition.
// Atomics were the wall (64M memory-side fp32 RMW = ~512MB/layer + op serialization).
// CSR mode (if ws_size allows ~197MB):
//   k_init: A=sym fp32, hb=bf16(A), ebb=bf16(eemb), cnt=0
//   k_hist/k_scan/k_fill: counting-sort edges by obj -> eS/eP/eO in CSR order
//   per layer: k_msg (edge-major MFMA MLP -> bf16 msg rows, coalesced, NO atomics)
//              k_agg (wave-per-node: 64 lanes=64 cols, fp32 segment-sum, hb refresh)
// Fallback (small ws): round-2 structure + bf16 h-mirror, fp32 atomics.

#define N_NODES 100000
#define NV_ELEMS (N_NODES * 64)
#define N_EDGES 1000000
#define EV_ELEMS (131075 * 64)   // VOCAB * ES
#define ES 64
#define TILE 32
#define NTILES (N_EDGES / TILE)

typedef __bf16 bf16x8 __attribute__((ext_vector_type(8)));
typedef __bf16 bf16x4 __attribute__((ext_vector_type(4)));
typedef float f32x4 __attribute__((ext_vector_type(4)));

__device__ __forceinline__ f32x4 mfma_16x16x32(bf16x8 a, bf16x8 b, f32x4 c) {
    return __builtin_amdgcn_mfma_f32_16x16x32_bf16(a, b, c, 0, 0, 0);
}

// GELU with A&S 7.1.26 erf (|err|<1.5e-7), HW rcp/exp.
__device__ __forceinline__ float gelu_fast(float v) {
    float u  = fabsf(v) * 0.70710678118654752f;
    float t  = __builtin_amdgcn_rcpf(fmaf(0.3275911f, u, 1.0f));
    float e  = __expf(-u * u);
    float p  = t * fmaf(t, fmaf(t, fmaf(t, fmaf(t, 1.061405429f, -1.453152027f),
                                        1.421413741f), -0.284496736f), 0.254829592f);
    float er = fmaf(-p, e, 1.0f);
    float s  = (v >= 0.0f) ? er : -er;
    return 0.5f * v * (1.0f + s);
}

__global__ void k_init(const float* __restrict__ sym, const float* __restrict__ eemb,
                       float* __restrict__ A, __bf16* __restrict__ hb,
                       __bf16* __restrict__ ebb, float* __restrict__ pooled,
                       int* __restrict__ cnt, int csr) {
    const int nv4 = NV_ELEMS / 4;
    const float4* s4 = (const float4*)sym;
    float4* a4 = (float4*)A;
    for (int i = blockIdx.x * blockDim.x + threadIdx.x; i < nv4;
         i += gridDim.x * blockDim.x) {
        float4 v = s4[i];
        a4[i] = v;
        bf16x4 p;
        p[0] = (__bf16)v.x; p[1] = (__bf16)v.y; p[2] = (__bf16)v.z; p[3] = (__bf16)v.w;
        *(bf16x4*)(hb + (size_t)i * 4) = p;
    }
    if (csr) {
        const int ev4 = EV_ELEMS / 4;
        const float4* e4 = (const float4*)eemb;
        for (int i = blockIdx.x * blockDim.x + threadIdx.x; i < ev4;
             i += gridDim.x * blockDim.x) {
            float4 v = e4[i];
            bf16x4 p;
            p[0] = (__bf16)v.x; p[1] = (__bf16)v.y; p[2] = (__bf16)v.z; p[3] = (__bf16)v.w;
            *(bf16x4*)(ebb + (size_t)i * 4) = p;
        }
        for (int i = blockIdx.x * blockDim.x + threadIdx.x; i < N_NODES;
             i += gridDim.x * blockDim.x)
            cnt[i] = 0;
    }
    if (blockIdx.x == 0 && threadIdx.x < ES) pooled[threadIdx.x] = 0.0f;
}

__global__ void k_h2b(const float* __restrict__ A, __bf16* __restrict__ hb) {
    const int nv4 = NV_ELEMS / 4;
    const float4* a4 = (const float4*)A;
    for (int i = blockIdx.x * blockDim.x + threadIdx.x; i < nv4;
         i += gridDim.x * blockDim.x) {
        float4 v = a4[i];
        bf16x4 p;
        p[0] = (__bf16)v.x; p[1] = (__bf16)v.y; p[2] = (__bf16)v.z; p[3] = (__bf16)v.w;
        *(bf16x4*)(hb + (size_t)i * 4) = p;
    }
}

// ---------------- CSR build ----------------
__global__ void k_hist(const int* __restrict__ obj, int* __restrict__ cnt) {
    int e = blockIdx.x * blockDim.x + threadIdx.x;
    if (e < N_EDGES) atomicAdd(&cnt[obj[e]], 1);
}

// single-block exclusive scan of cnt[100000] -> off[], cur[]; off[N]=total
__global__ __launch_bounds__(1024) void k_scan(const int* __restrict__ cnt,
                                               int* __restrict__ off,
                                               int* __restrict__ cur) {
    __shared__ int sp[1024];
    const int t = threadIdx.x;
    const int CHUNK = (N_NODES + 1023) / 1024;   // 98
    const int base = t * CHUNK;
    int s = 0;
    for (int i = 0; i < CHUNK; ++i) {
        int g = base + i;
        if (g < N_NODES) s += cnt[g];
    }
    sp[t] = s;
    __syncthreads();
    for (int d = 1; d < 1024; d <<= 1) {
        int v = (t >= d) ? sp[t - d] : 0;
        __syncthreads();
        sp[t] += v;
        __syncthreads();
    }
    int run = sp[t] - s;   // exclusive prefix of this chunk
    for (int i = 0; i < CHUNK; ++i) {
        int g = base + i;
        if (g < N_NODES) {
            off[g] = run;
            cur[g] = run;
            run += cnt[g];
        }
    }
    if (t == 1023) off[N_NODES] = sp[1023];
}

// place each edge's (subj,pred,obj) at its CSR slot
__global__ void k_fill(const int* __restrict__ subj, const int* __restrict__ pred,
                       const int* __restrict__ obj, int* __restrict__ cur,
                       int* __restrict__ eS, int* __restrict__ eP, int* __restrict__ eO) {
    int e = blockIdx.x * blockDim.x + threadIdx.x;
    if (e >= N_EDGES) return;
    int o = obj[e];
    int pos = atomicAdd(&cur[o], 1);
    eS[pos] = subj[e];
    eP[pos] = pred[e];
    eO[pos] = o;
}

// ---------------- phase 1: edge-major MLP -> msg (bf16), no scatter ----------------
__global__ __launch_bounds__(256, 4) void k_msg(
    const int* __restrict__ eS, const int* __restrict__ eP, const int* __restrict__ eO,
    const __bf16* __restrict__ hb, const __bf16* __restrict__ ebb,
    __bf16* __restrict__ msgb,
    const float* __restrict__ w1, const float* __restrict__ b1,
    const float* __restrict__ w2, const float* __restrict__ b2) {
    __shared__ __bf16 sX[TILE][200];    // 12.8 KB
    __shared__ __bf16 sHm[TILE][136];   // 8.7 KB
    __shared__ __bf16 sMsg[TILE][64];   // 4.0 KB

    const int tid = threadIdx.x;
    const int w   = tid >> 6;
    const int l   = tid & 63;
    const int lg  = l >> 4;
    const int lc  = l & 15;

    // weight fragments in registers (A/B share the k = 32kt+8lg+i lane assignment)
    bf16x8 wb1[6][2];
#pragma unroll
    for (int kt = 0; kt < 6; ++kt)
#pragma unroll
        for (int nt = 0; nt < 2; ++nt) {
            bf16x8 f;
#pragma unroll
            for (int i = 0; i < 8; ++i) {
                int k   = kt * 32 + lg * 8 + i;
                int col = w * 32 + nt * 16 + lc;
                f[i] = (__bf16)w1[k * 128 + col];
            }
            wb1[kt][nt] = f;
        }
    bf16x8 wb2[4];
#pragma unroll
    for (int kt = 0; kt < 4; ++kt) {
        bf16x8 f;
#pragma unroll
        for (int i = 0; i < 8; ++i) {
            int k = kt * 32 + lg * 8 + i;
            f[i] = (__bf16)w2[k * 64 + w * 16 + lc];
        }
        wb2[kt] = f;
    }
    const float b1c0 = b1[w * 32 + lc];
    const float b1c1 = b1[w * 32 + 16 + lc];
    const float b2v  = b2[w * 16 + lc];

    // gather plan: 96 segments (32 rows x 3 parts), 16 lanes each
    const int g16 = tid >> 4, l16 = tid & 15;
    int rowA[6], partA[6];
    const int* ipA[6];
    const __bf16* tabA[6];
#pragma unroll
    for (int it = 0; it < 6; ++it) {
        int seg = it * 16 + g16;
        rowA[it]  = seg / 3;
        partA[it] = seg - 3 * rowA[it];
        ipA[it]  = partA[it] == 0 ? eS : (partA[it] == 1 ? eP : eO);
        tabA[it] = partA[it] == 1 ? ebb : hb;
    }

    for (int tile = blockIdx.x; tile < NTILES; tile += gridDim.x) {
        const int j0 = tile * TILE;

        // ---- gather X = [hb[subj] | ebb[pred] | hb[obj]] (all bf16, 8B/lane) ----
#pragma unroll
        for (int it = 0; it < 6; ++it) {
            int idx = ipA[it][j0 + rowA[it]];
            bf16x4 v = *(const bf16x4*)(tabA[it] + (size_t)idx * ES + l16 * 4);
            *(bf16x4*)&sX[rowA[it]][partA[it] * 64 + l16 * 4] = v;
        }
        __syncthreads();

        // ---- GEMM1: (32x192) @ W1 -> wave's 32x32 hmid slice ----
        f32x4 acc1[2][2];
#pragma unroll
        for (int mt = 0; mt < 2; ++mt)
#pragma unroll
            for (int nt = 0; nt < 2; ++nt) acc1[mt][nt] = (f32x4){0.f, 0.f, 0.f, 0.f};
#pragma unroll
        for (int kt = 0; kt < 6; ++kt) {
#pragma unroll
            for (int mt = 0; mt < 2; ++mt) {
                bf16x8 a = *(const bf16x8*)&sX[mt * 16 + lc][kt * 32 + lg * 8];
                acc1[mt][0] = mfma_16x16x32(a, wb1[kt][0], acc1[mt][0]);
                acc1[mt][1] = mfma_16x16x32(a, wb1[kt][1], acc1[mt][1]);
            }
        }

        // ---- bias + GELU -> hmid LDS ----
#pragma unroll
        for (int mt = 0; mt < 2; ++mt)
#pragma unroll
            for (int nt = 0; nt < 2; ++nt) {
                float bias = nt ? b1c1 : b1c0;
#pragma unroll
                for (int r = 0; r < 4; ++r) {
                    float g = gelu_fast(acc1[mt][nt][r] + bias);
                    sHm[mt * 16 + lg * 4 + r][w * 32 + nt * 16 + lc] = (__bf16)g;
                }
            }
        __syncthreads();

        // ---- GEMM2: hmid(32x128) @ W2[:,16w:16w+16) ----
        f32x4 acc2[2];
        acc2[0] = (f32x4){0.f, 0.f, 0.f, 0.f};
        acc2[1] = (f32x4){0.f, 0.f, 0.f, 0.f};
#pragma unroll
        for (int kt = 0; kt < 4; ++kt) {
#pragma unroll
            for (int mt = 0; mt < 2; ++mt) {
                bf16x8 a = *(const bf16x8*)&sHm[mt * 16 + lc][kt * 32 + lg * 8];
                acc2[mt] = mfma_16x16x32(a, wb2[kt], acc2[mt]);
            }
        }

        // ---- + b2 -> sMsg, then coalesced 16B/thread store to msgb ----
#pragma unroll
        for (int mt = 0; mt < 2; ++mt)
#pragma unroll
            for (int r = 0; r < 4; ++r)
                sMsg[mt * 16 + lg * 4 + r][w * 16 + lc] = (__bf16)(acc2[mt][r] + b2v);
        __syncthreads();
        {
            int row = tid >> 3, o8 = (tid & 7) * 8;
            *(bf16x8*)(msgb + (size_t)(j0 + row) * ES + o8) = *(bf16x8*)&sMsg[row][o8];
        }
        __syncthreads();
    }
}

// ---------------- phase 2: wave-per-node segment sum, fused hb refresh ----------------
__global__ __launch_bounds__(256) void k_agg(const int* __restrict__ off,
                                             const __bf16* __restrict__ msgb,
                                             float* __restrict__ A,
                                             __bf16* __restrict__ hb) {
    const int w    = threadIdx.x >> 6;
    const int lane = threadIdx.x & 63;
    const int n    = blockIdx.x * 4 + w;
    if (n >= N_NODES) return;
    const int s  = off[n];
    const int e2 = off[n + 1];
    float a0 = 0.f, a1 = 0.f;
    int j = s;
    for (; j + 1 < e2; j += 2) {
        a0 += (float)msgb[(size_t)j * ES + lane];
        a1 += (float)msgb[(size_t)(j + 1) * ES + lane];
    }
    if (j < e2) a0 += (float)msgb[(size_t)j * ES + lane];
    const size_t o = (size_t)n * ES + lane;
    float acc = A[o] + a0 + a1;
    A[o]  = acc;
    hb[o] = (__bf16)acc;
}

// ---------------- fallback: round-2 edge kernel with bf16 h-mirror gathers ----------------
__global__ __launch_bounds__(256, 4) void k_edges_at(
    const int* __restrict__ subj, const int* __restrict__ pred, const int* __restrict__ obj,
    const __bf16* __restrict__ hb, float* __restrict__ A,
    const float* __restrict__ eemb,
    const float* __restrict__ w1, const float* __restrict__ b1,
    const float* __restrict__ w2, const float* __restrict__ b2) {
    __shared__ __bf16 sX[TILE][200];
    __shared__ __bf16 sHm[TILE][136];
    __shared__ int    sO[TILE];

    const int tid = threadIdx.x;
    const int w   = tid >> 6;
    const int l   = tid & 63;
    const int lg  = l >> 4;
    const int lc  = l & 15;

    bf16x8 wb1[6][2];
#pragma unroll
    for (int kt = 0; kt < 6; ++kt)
#pragma unroll
        for (int nt = 0; nt < 2; ++nt) {
            bf16x8 f;
#pragma unroll
            for (int i = 0; i < 8; ++i) {
                int k   = kt * 32 + lg * 8 + i;
                int col = w * 32 + nt * 16 + lc;
                f[i] = (__bf16)w1[k * 128 + col];
            }
            wb1[kt][nt] = f;
        }
    bf16x8 wb2[4];
#pragma unroll
    for (int kt = 0; kt < 4; ++kt) {
        bf16x8 f;
#pragma unroll
        for (int i = 0; i < 8; ++i) {
            int k = kt * 32 + lg * 8 + i;
            f[i] = (__bf16)w2[k * 64 + w * 16 + lc];
        }
        wb2[kt] = f;
    }
    const float b1c0 = b1[w * 32 + lc];
    const float b1c1 = b1[w * 32 + 16 + lc];
    const int   scol = w * 16 + lc;
    const float b2v  = b2[scol];

    const int g16 = tid >> 4, l16 = tid & 15;
    int rowA[6], partA[6];
#pragma unroll
    for (int it = 0; it < 6; ++it) {
        int seg = it * 16 + g16;
        rowA[it] = seg / 3;
        partA[it] = seg - 3 * rowA[it];
    }

    for (int tile = blockIdx.x; tile < NTILES; tile += gridDim.x) {
        const int e0 = tile * TILE;
        if (tid < TILE) sO[tid] = obj[e0 + tid];
#pragma unroll
        for (int it = 0; it < 6; ++it) {
            int row = rowA[it], part = partA[it];
            if (part == 1) {
                int idx = pred[e0 + row];
                float4 v = *(const float4*)(eemb + (size_t)idx * ES + l16 * 4);
                bf16x4 p;
                p[0] = (__bf16)v.x; p[1] = (__bf16)v.y;
                p[2] = (__bf16)v.z; p[3] = (__bf16)v.w;
                *(bf16x4*)&sX[row][64 + l16 * 4] = p;
            } else {
                int idx = (part == 0 ? subj : obj)[e0 + row];
                *(bf16x4*)&sX[row][part * 64 + l16 * 4] =
                    *(const bf16x4*)(hb + (size_t)idx * ES + l16 * 4);
            }
        }
        __syncthreads();

        f32x4 acc1[2][2];
#pragma unroll
        for (int mt = 0; mt < 2; ++mt)
#pragma unroll
            for (int nt = 0; nt < 2; ++nt) acc1[mt][nt] = (f32x4){0.f, 0.f, 0.f, 0.f};
#pragma unroll
        for (int kt = 0; kt < 6; ++kt) {
#pragma unroll
            for (int mt = 0; mt < 2; ++mt) {
                bf16x8 a = *(const bf16x8*)&sX[mt * 16 + lc][kt * 32 + lg * 8];
                acc1[mt][0] = mfma_16x16x32(a, wb1[kt][0], acc1[mt][0]);
                acc1[mt][1] = mfma_16x16x32(a, wb1[kt][1], acc1[mt][1]);
            }
        }
#pragma unroll
        for (int mt = 0; mt < 2; ++mt)
#pragma unroll
            for (int nt = 0; nt < 2; ++nt) {
                float bias = nt ? b1c1 : b1c0;
#pragma unroll
                for (int r = 0; r < 4; ++r) {
                    float g = gelu_fast(acc1[mt][nt][r] + bias);
                    sHm[mt * 16 + lg * 4 + r][w * 32 + nt * 16 + lc] = (__bf16)g;
                }
            }
        __syncthreads();

        f32x4 acc2[2];
        acc2[0] = (f32x4){0.f, 0.f, 0.f, 0.f};
        acc2[1] = (f32x4){0.f, 0.f, 0.f, 0.f};
#pragma unroll
        for (int kt = 0; kt < 4; ++kt) {
#pragma unroll
            for (int mt = 0; mt < 2; ++mt) {
                bf16x8 a = *(const bf16x8*)&sHm[mt * 16 + lc][kt * 32 + lg * 8];
                acc2[mt] = mfma_16x16x32(a, wb2[kt], acc2[mt]);
            }
        }
#pragma unroll
        for (int mt = 0; mt < 2; ++mt)
#pragma unroll
            for (int r = 0; r < 4; ++r) {
                int row = mt * 16 + lg * 4 + r;
                atomicAdd(&A[(size_t)sO[row] * ES + scol], acc2[mt][r] + b2v);
            }
        __syncthreads();
    }
}

__global__ void k_pool(const float* __restrict__ h, float* __restrict__ pooled) {
    __shared__ float sm[256];
    float acc = 0.f;
    for (int idx = blockIdx.x * 256 + threadIdx.x; idx < NV_ELEMS; idx += gridDim.x * 256)
        acc += h[idx];
    sm[threadIdx.x] = acc;
    __syncthreads();
    if (threadIdx.x < 64) {
        float s = sm[threadIdx.x] + sm[threadIdx.x + 64] + sm[threadIdx.x + 128] +
                  sm[threadIdx.x + 192];
        atomicAdd(&pooled[threadIdx.x], s);
    }
}

__global__ void k_final(const float* __restrict__ pooled, const float* __restrict__ w,
                        const float* __restrict__ b, float* __restrict__ out) {
    __shared__ float sp[64];
    if (threadIdx.x < 64) sp[threadIdx.x] = pooled[threadIdx.x] * (1.0f / N_NODES);
    __syncthreads();
    const int c = threadIdx.x;
    float s = b[c];
#pragma unroll
    for (int j = 0; j < 64; ++j) s += sp[j] * w[j * 256 + c];
    out[c] = s;
}

extern "C" void kernel_launch(void* const* d_in, const int* in_sizes, int n_in,
                              void* d_out, int out_size, void* d_ws, size_t ws_size,
                              hipStream_t stream) {
    const int*   subj = (const int*)d_in[0];
    const int*   pred = (const int*)d_in[1];
    const int*   obj  = (const int*)d_in[2];
    const float* sym  = (const float*)d_in[3];
    const float* eemb = (const float*)d_in[4];
    const float* w1   = (const float*)d_in[5];
    const float* b1   = (const float*)d_in[6];
    const float* w2   = (const float*)d_in[7];
    const float* b2   = (const float*)d_in[8];
    const float* lw   = (const float*)d_in[9];
    const float* lb   = (const float*)d_in[10];
    float* out = (float*)d_out;

    // ---- ws layout ----
    char* p = (char*)d_ws;
    float*  A      = (float*)p;          p += (size_t)NV_ELEMS * 4;   //  25,600,000
    __bf16* hb     = (__bf16*)p;         p += (size_t)NV_ELEMS * 2;   //  12,800,000
    float*  pooled = (float*)p;          p += 256;                    //  (fallback ends here)
    __bf16* ebb    = (__bf16*)p;         p += (size_t)EV_ELEMS * 2;   //  16,777,600
    __bf16* msgb   = (__bf16*)p;         p += (size_t)N_EDGES * ES * 2; // 128,000,000
    int*    cnt    = (int*)p;            p += (size_t)N_NODES * 4;
    int*    off    = (int*)p;            p += (size_t)(N_NODES + 4) * 4;
    int*    cur    = (int*)p;            p += (size_t)N_NODES * 4;
    int*    eS     = (int*)p;            p += (size_t)N_EDGES * 4;
    int*    eP     = (int*)p;            p += (size_t)N_EDGES * 4;
    int*    eO     = (int*)p;            p += (size_t)N_EDGES * 4;
    const size_t need = (size_t)(p - (char*)d_ws);
    const int csr = (ws_size >= need) ? 1 : 0;

    k_init<<<2048, 256, 0, stream>>>(sym, eemb, A, hb, csr ? ebb : hb, pooled,
                                     csr ? cnt : (int*)pooled, csr);
    if (csr) {
        const int EB = (N_EDGES + 255) / 256;
        k_hist<<<EB, 256, 0, stream>>>(obj, cnt);
        k_scan<<<1, 1024, 0, stream>>>(cnt, off, cur);
        k_fill<<<EB, 256, 0, stream>>>(subj, pred, obj, cur, eS, eP, eO);
        const int NB = (N_NODES + 3) / 4;
        // layer 0
        k_msg<<<2048, 256, 0, stream>>>(eS, eP, eO, hb, ebb, msgb, w1, b1, w2, b2);
        k_agg<<<NB, 256, 0, stream>>>(off, msgb, A, hb);
        // layer 1
        k_msg<<<2048, 256, 0, stream>>>(eS, eP, eO, hb, ebb, msgb,
                                        w1 + 192 * 128, b1 + 128, w2 + 128 * 64, b2 + 64);
        k_agg<<<NB, 256, 0, stream>>>(off, msgb, A, hb);
    } else {
        k_edges_at<<<2048, 256, 0, stream>>>(subj, pred, obj, hb, A, eemb,
                                             w1, b1, w2, b2);
        k_h2b<<<2048, 256, 0, stream>>>(A, hb);
        k_edges_at<<<2048, 256, 0, stream>>>(subj, pred, obj, hb, A, eemb,
                                             w1 + 192 * 128, b1 + 128,
                                             w2 + 128 * 64, b2 + 64);
    }
    k_pool<<<256, 256, 0, stream>>>(A, pooled);
    k_final<<<1, 256, 0, stream>>>(pooled, lw, lb, out);
}

// Round 5
// 496.100 us; speedup vs baseline: 2.3897x; 1.9111x over previous
//
#include <hip/hip_runtime.h>
#include <hip/hip_bf16.h>

// SymbolicGNN, CSR two-phase, v5.
// - Hierarchical 3-kernel scan (was: 262us single-block scan).
// - k_msg: transposed MFMA (mfma(W,X)) so output regs hold 4 consecutive out-cols
//   -> packed ds_write_b64 for hmid, direct 8B global stores for msg (no sMsg LDS,
//   2 barriers/tile instead of 3).
// - tanh-GELU (|err|~1e-3 << bf16 rounding; output mean-pooled over 100k nodes).
// - 1-tile register prefetch of gathers (bf16-only, 12 VGPRs; round-3 spill was
//   fp32 rf[6] + pointer arrays -> ~140 live regs; this plan stays ~120).

#define N_NODES 100000
#define NV_ELEMS (N_NODES * 64)
#define N_EDGES 1000000
#define EV_ELEMS (131075 * 64)   // VOCAB * ES
#define ES 64
#define TILE 32
#define NTILES (N_EDGES / TILE)
#define SCAN_B 1024
#define SCAN_NB ((N_NODES + SCAN_B - 1) / SCAN_B)   // 98

typedef __bf16 bf16x8 __attribute__((ext_vector_type(8)));
typedef __bf16 bf16x4 __attribute__((ext_vector_type(4)));
typedef float f32x4 __attribute__((ext_vector_type(4)));

__device__ __forceinline__ f32x4 mfma_16x16x32(bf16x8 a, bf16x8 b, f32x4 c) {
    return __builtin_amdgcn_mfma_f32_16x16x32_bf16(a, b, c, 0, 0, 0);
}

// tanh-form GELU: 0.5v(1+tanh(0.79788456(v+0.044715v^3))). Sign-split so
// exp2 arg is always <=0 (no overflow->NaN). ~11 VALU ops, 2 transcendental.
__device__ __forceinline__ float gelu_tanh(float v) {
    float x2 = v * v;
    float u  = v * fmaf(x2, 0.0356774081f, 0.7978845608f);
    float au = fabsf(u);
    float t  = __builtin_amdgcn_exp2f(au * -2.8853900818f);  // e^{-2|u|} in (0,1]
    float r  = __builtin_amdgcn_rcpf(1.0f + t);
    float th = fmaf(-2.0f * t, r, 1.0f);                     // tanh(|u|)
    float s  = (v >= 0.0f) ? th : -th;
    float hv = 0.5f * v;
    return fmaf(hv, s, hv);
}

__global__ void k_init(const float* __restrict__ sym, const float* __restrict__ eemb,
                       float* __restrict__ A, __bf16* __restrict__ hb,
                       __bf16* __restrict__ ebb, float* __restrict__ pooled,
                       int* __restrict__ cnt) {
    const int nv4 = NV_ELEMS / 4;
    const float4* s4 = (const float4*)sym;
    float4* a4 = (float4*)A;
    for (int i = blockIdx.x * blockDim.x + threadIdx.x; i < nv4;
         i += gridDim.x * blockDim.x) {
        float4 v = s4[i];
        a4[i] = v;
        bf16x4 p;
        p[0] = (__bf16)v.x; p[1] = (__bf16)v.y; p[2] = (__bf16)v.z; p[3] = (__bf16)v.w;
        *(bf16x4*)(hb + (size_t)i * 4) = p;
    }
    const int ev4 = EV_ELEMS / 4;
    const float4* e4 = (const float4*)eemb;
    for (int i = blockIdx.x * blockDim.x + threadIdx.x; i < ev4;
         i += gridDim.x * blockDim.x) {
        float4 v = e4[i];
        bf16x4 p;
        p[0] = (__bf16)v.x; p[1] = (__bf16)v.y; p[2] = (__bf16)v.z; p[3] = (__bf16)v.w;
        *(bf16x4*)(ebb + (size_t)i * 4) = p;
    }
    for (int i = blockIdx.x * blockDim.x + threadIdx.x; i < N_NODES;
         i += gridDim.x * blockDim.x)
        cnt[i] = 0;
    if (blockIdx.x == 0 && threadIdx.x < ES) pooled[threadIdx.x] = 0.0f;
}

// ---------------- CSR build ----------------
__global__ void k_hist(const int* __restrict__ obj, int* __restrict__ cnt) {
    int e = blockIdx.x * blockDim.x + threadIdx.x;
    if (e < N_EDGES) atomicAdd(&cnt[obj[e]], 1);
}

// per-block 1024-wide Hillis-Steele scan; writes local-exclusive prefix + block sum
__global__ __launch_bounds__(1024) void k_scanA(const int* __restrict__ cnt,
                                                int* __restrict__ off,
                                                int* __restrict__ bsum) {
    __shared__ int sp[SCAN_B];
    const int t = threadIdx.x;
    const int g = blockIdx.x * SCAN_B + t;
    int v = (g < N_NODES) ? cnt[g] : 0;
    sp[t] = v;
    __syncthreads();
#pragma unroll
    for (int d = 1; d < SCAN_B; d <<= 1) {
        int x = (t >= d) ? sp[t - d] : 0;
        __syncthreads();
        sp[t] += x;
        __syncthreads();
    }
    if (g < N_NODES) off[g] = sp[t] - v;
    if (t == SCAN_B - 1) bsum[blockIdx.x] = sp[t];
}

__global__ void k_scanB(const int* __restrict__ bsum, int* __restrict__ boff) {
    __shared__ int s[SCAN_NB];
    const int t = threadIdx.x;
    for (int i = t; i < SCAN_NB; i += 64) s[i] = bsum[i];
    __syncthreads();
    if (t == 0) {
        int run = 0;
        for (int b = 0; b < SCAN_NB; ++b) { int v = s[b]; s[b] = run; run += v; }
    }
    __syncthreads();
    for (int i = t; i < SCAN_NB; i += 64) boff[i] = s[i];
}

__global__ __launch_bounds__(1024) void k_scanC(int* __restrict__ off,
                                                const int* __restrict__ boff,
                                                int* __restrict__ cur) {
    const int g = blockIdx.x * SCAN_B + threadIdx.x;
    if (g < N_NODES) {
        int o = off[g] + boff[blockIdx.x];
        off[g] = o;
        cur[g] = o;
    }
    if (g == 0) off[N_NODES] = N_EDGES;
}

__global__ void k_fill(const int* __restrict__ subj, const int* __restrict__ pred,
                       const int* __restrict__ obj, int* __restrict__ cur,
                       int* __restrict__ eS, int* __restrict__ eP, int* __restrict__ eO) {
    int e = blockIdx.x * blockDim.x + threadIdx.x;
    if (e >= N_EDGES) return;
    int o = obj[e];
    int pos = atomicAdd(&cur[o], 1);
    eS[pos] = subj[e];
    eP[pos] = pred[e];
    eO[pos] = o;
}

// ---------------- phase 1: edge-major MLP -> msg rows (bf16, CSR order) ----------------
__global__ __launch_bounds__(256, 4) void k_msg(
    const int* __restrict__ eS, const int* __restrict__ eP, const int* __restrict__ eO,
    const __bf16* __restrict__ hb, const __bf16* __restrict__ ebb,
    __bf16* __restrict__ msgb,
    const float* __restrict__ w1, const float* __restrict__ b1,
    const float* __restrict__ w2, const float* __restrict__ b2) {
    __shared__ __bf16 sX[TILE][200];    // 12.8 KB, stride 400B -> 2-way banks on b128
    __shared__ __bf16 sHm[TILE][136];   // 8.7 KB, stride 272B -> 2-way banks

    const int tid = threadIdx.x;
    const int w   = tid >> 6;
    const int l   = tid & 63;
    const int lg  = l >> 4;
    const int lc  = l & 15;

    // weight fragments (A/B share k = 32kt+8lg+i lane assignment; permutation cancels)
    bf16x8 wb1[6][2];
#pragma unroll
    for (int kt = 0; kt < 6; ++kt)
#pragma unroll
        for (int nt = 0; nt < 2; ++nt) {
            bf16x8 f;
#pragma unroll
            for (int i = 0; i < 8; ++i) {
                int k   = kt * 32 + lg * 8 + i;
                int col = w * 32 + nt * 16 + lc;
                f[i] = (__bf16)w1[k * 128 + col];
            }
            wb1[kt][nt] = f;
        }
    bf16x8 wb2[4];
#pragma unroll
    for (int kt = 0; kt < 4; ++kt) {
        bf16x8 f;
#pragma unroll
        for (int i = 0; i < 8; ++i) {
            int k = kt * 32 + lg * 8 + i;
            f[i] = (__bf16)w2[k * 64 + w * 16 + lc];
        }
        wb2[kt] = f;
    }
    // transposed epilogue: this thread's 4 consecutive out-cols start at lg*4
    f32x4 b1q[2];
    b1q[0] = *(const f32x4*)(b1 + w * 32 + lg * 4);
    b1q[1] = *(const f32x4*)(b1 + w * 32 + 16 + lg * 4);
    f32x4 b2q = *(const f32x4*)(b2 + w * 16 + lg * 4);

    // gather plan: part = it/2 (compile-time), rows g16 and g16+16
    const int g16 = tid >> 4, l16 = tid & 15;
    const int row0 = g16, row1 = g16 + 16;

    int    idx[6];
    bf16x4 rb[6];

#define LOAD_IDX(J0)                         \
    do {                                     \
        idx[0] = eS[(J0) + row0];            \
        idx[1] = eS[(J0) + row1];            \
        idx[2] = eP[(J0) + row0];            \
        idx[3] = eP[(J0) + row1];            \
        idx[4] = eO[(J0) + row0];            \
        idx[5] = eO[(J0) + row1];            \
    } while (0)
#define GATHER()                                                            \
    do {                                                                    \
        rb[0] = *(const bf16x4*)(hb  + (size_t)idx[0] * ES + l16 * 4);      \
        rb[1] = *(const bf16x4*)(hb  + (size_t)idx[1] * ES + l16 * 4);      \
        rb[2] = *(const bf16x4*)(ebb + (size_t)idx[2] * ES + l16 * 4);      \
        rb[3] = *(const bf16x4*)(ebb + (size_t)idx[3] * ES + l16 * 4);      \
        rb[4] = *(const bf16x4*)(hb  + (size_t)idx[4] * ES + l16 * 4);      \
        rb[5] = *(const bf16x4*)(hb  + (size_t)idx[5] * ES + l16 * 4);      \
    } while (0)

    int tile = blockIdx.x;
    int j0   = tile * TILE;
    LOAD_IDX(j0);
    GATHER();

    for (; tile < NTILES; tile += gridDim.x) {
        const int jn = (tile + (int)gridDim.x < NTILES) ? (tile + gridDim.x) * TILE : j0;

        // ---- stage current X; start next tile's index loads ----
        *(bf16x4*)&sX[row0][      l16 * 4] = rb[0];
        *(bf16x4*)&sX[row1][      l16 * 4] = rb[1];
        *(bf16x4*)&sX[row0][ 64 + l16 * 4] = rb[2];
        *(bf16x4*)&sX[row1][ 64 + l16 * 4] = rb[3];
        *(bf16x4*)&sX[row0][128 + l16 * 4] = rb[4];
        *(bf16x4*)&sX[row1][128 + l16 * 4] = rb[5];
        LOAD_IDX(jn);
        __syncthreads();   // bar1: sX ready; prior GEMM2's sHm reads all done

        // ---- GEMM1 (transposed): acc1[nt][mt] lane holds hmid[col][edge-row] ----
        f32x4 acc1[2][2];
#pragma unroll
        for (int nt = 0; nt < 2; ++nt)
#pragma unroll
            for (int mt = 0; mt < 2; ++mt) acc1[nt][mt] = (f32x4){0.f, 0.f, 0.f, 0.f};
#pragma unroll
        for (int kt = 0; kt < 6; ++kt) {
            bf16x8 x0 = *(const bf16x8*)&sX[lc][kt * 32 + lg * 8];
            bf16x8 x1 = *(const bf16x8*)&sX[16 + lc][kt * 32 + lg * 8];
            acc1[0][0] = mfma_16x16x32(wb1[kt][0], x0, acc1[0][0]);
            acc1[0][1] = mfma_16x16x32(wb1[kt][0], x1, acc1[0][1]);
            acc1[1][0] = mfma_16x16x32(wb1[kt][1], x0, acc1[1][0]);
            acc1[1][1] = mfma_16x16x32(wb1[kt][1], x1, acc1[1][1]);
        }

        // ---- prefetch next tile's gather rows (hides L3 latency under GELU+GEMM2) ----
        GATHER();

        // ---- bias + GELU, packed b64 write: 4 consecutive hmid cols per lane ----
#pragma unroll
        for (int nt = 0; nt < 2; ++nt)
#pragma unroll
            for (int mt = 0; mt < 2; ++mt) {
                bf16x4 hq;
#pragma unroll
                for (int r = 0; r < 4; ++r)
                    hq[r] = (__bf16)gelu_tanh(acc1[nt][mt][r] + b1q[nt][r]);
                *(bf16x4*)&sHm[mt * 16 + lc][w * 32 + nt * 16 + lg * 4] = hq;
            }
        __syncthreads();   // bar2: sHm ready

        // ---- GEMM2 (transposed): lane holds msg[col][edge-row], direct 8B store ----
        f32x4 acc2[2];
        acc2[0] = (f32x4){0.f, 0.f, 0.f, 0.f};
        acc2[1] = (f32x4){0.f, 0.f, 0.f, 0.f};
#pragma unroll
        for (int kt = 0; kt < 4; ++kt) {
            bf16x8 h0 = *(const bf16x8*)&sHm[lc][kt * 32 + lg * 8];
            bf16x8 h1 = *(const bf16x8*)&sHm[16 + lc][kt * 32 + lg * 8];
            acc2[0] = mfma_16x16x32(wb2[kt], h0, acc2[0]);
            acc2[1] = mfma_16x16x32(wb2[kt], h1, acc2[1]);
        }
#pragma unroll
        for (int rn = 0; rn < 2; ++rn) {
            bf16x4 mq;
#pragma unroll
            for (int r = 0; r < 4; ++r)
                mq[r] = (__bf16)(acc2[rn][r] + b2q[r]);
            *(bf16x4*)(msgb + (size_t)(j0 + rn * 16 + lc) * ES + w * 16 + lg * 4) = mq;
        }
        j0 = jn;
    }
#undef LOAD_IDX
#undef GATHER
}

// ---------------- phase 2: wave-per-node segment sum, fused hb refresh ----------------
__global__ __launch_bounds__(256) void k_agg(const int* __restrict__ off,
                                             const __bf16* __restrict__ msgb,
                                             float* __restrict__ A,
                                             __bf16* __restrict__ hb) {
    const int w    = threadIdx.x >> 6;
    const int lane = threadIdx.x & 63;
    const int n    = blockIdx.x * 4 + w;
    if (n >= N_NODES) return;
    const int s  = off[n];
    const int e2 = off[n + 1];
    float a0 = 0.f, a1 = 0.f;
    int j = s;
    for (; j + 1 < e2; j += 2) {
        a0 += (float)msgb[(size_t)j * ES + lane];
        a1 += (float)msgb[(size_t)(j + 1) * ES + lane];
    }
    if (j < e2) a0 += (float)msgb[(size_t)j * ES + lane];
    const size_t o = (size_t)n * ES + lane;
    float acc = A[o] + a0 + a1;
    A[o]  = acc;
    hb[o] = (__bf16)acc;
}

__global__ void k_pool(const float* __restrict__ h, float* __restrict__ pooled) {
    __shared__ float sm[256];
    float acc = 0.f;
    for (int idx = blockIdx.x * 256 + threadIdx.x; idx < NV_ELEMS; idx += gridDim.x * 256)
        acc += h[idx];
    sm[threadIdx.x] = acc;
    __syncthreads();
    if (threadIdx.x < 64) {
        float s = sm[threadIdx.x] + sm[threadIdx.x + 64] + sm[threadIdx.x + 128] +
                  sm[threadIdx.x + 192];
        atomicAdd(&pooled[threadIdx.x], s);
    }
}

__global__ void k_final(const float* __restrict__ pooled, const float* __restrict__ w,
                        const float* __restrict__ b, float* __restrict__ out) {
    __shared__ float sp[64];
    if (threadIdx.x < 64) sp[threadIdx.x] = pooled[threadIdx.x] * (1.0f / N_NODES);
    __syncthreads();
    const int c = threadIdx.x;
    float s = b[c];
#pragma unroll
    for (int j = 0; j < 64; ++j) s += sp[j] * w[j * 256 + c];
    out[c] = s;
}

extern "C" void kernel_launch(void* const* d_in, const int* in_sizes, int n_in,
                              void* d_out, int out_size, void* d_ws, size_t ws_size,
                              hipStream_t stream) {
    const int*   subj = (const int*)d_in[0];
    const int*   pred = (const int*)d_in[1];
    const int*   obj  = (const int*)d_in[2];
    const float* sym  = (const float*)d_in[3];
    const float* eemb = (const float*)d_in[4];
    const float* w1   = (const float*)d_in[5];
    const float* b1   = (const float*)d_in[6];
    const float* w2   = (const float*)d_in[7];
    const float* b2   = (const float*)d_in[8];
    const float* lw   = (const float*)d_in[9];
    const float* lb   = (const float*)d_in[10];
    float* out = (float*)d_out;

    // ---- ws layout (same as round 4, confirmed to fit; + tiny scan buffers) ----
    char* p = (char*)d_ws;
    float*  A      = (float*)p;   p += (size_t)NV_ELEMS * 4;
    __bf16* hb     = (__bf16*)p;  p += (size_t)NV_ELEMS * 2;
    float*  pooled = (float*)p;   p += 256;
    __bf16* ebb    = (__bf16*)p;  p += (size_t)EV_ELEMS * 2;
    __bf16* msgb   = (__bf16*)p;  p += (size_t)N_EDGES * ES * 2;
    int*    cnt    = (int*)p;     p += (size_t)N_NODES * 4;
    int*    off    = (int*)p;     p += (size_t)(N_NODES + 4) * 4;
    int*    cur    = (int*)p;     p += (size_t)N_NODES * 4;
    int*    eS     = (int*)p;     p += (size_t)N_EDGES * 4;
    int*    eP     = (int*)p;     p += (size_t)N_EDGES * 4;
    int*    eO     = (int*)p;     p += (size_t)N_EDGES * 4;
    int*    bsum   = (int*)p;     p += (size_t)SCAN_NB * 4;
    int*    boff   = (int*)p;     p += (size_t)SCAN_NB * 4;

    const int EB = (N_EDGES + 255) / 256;
    const int NB = (N_NODES + 3) / 4;

    k_init<<<2048, 256, 0, stream>>>(sym, eemb, A, hb, ebb, pooled, cnt);
    k_hist<<<EB, 256, 0, stream>>>(obj, cnt);
    k_scanA<<<SCAN_NB, SCAN_B, 0, stream>>>(cnt, off, bsum);
    k_scanB<<<1, 64, 0, stream>>>(bsum, boff);
    k_scanC<<<SCAN_NB, SCAN_B, 0, stream>>>(off, boff, cur);
    k_fill<<<EB, 256, 0, stream>>>(subj, pred, obj, cur, eS, eP, eO);
    // layer 0
    k_msg<<<1024, 256, 0, stream>>>(eS, eP, eO, hb, ebb, msgb, w1, b1, w2, b2);
    k_agg<<<NB, 256, 0, stream>>>(off, msgb, A, hb);
    // layer 1
    k_msg<<<1024, 256, 0, stream>>>(eS, eP, eO, hb, ebb, msgb,
                                    w1 + 192 * 128, b1 + 128, w2 + 128 * 64, b2 + 64);
    k_agg<<<NB, 256, 0, stream>>>(off, msgb, A, hb);
    // pool + head
    k_pool<<<256, 256, 0, stream>>>(A, pooled);
    k_final<<<1, 256, 0, stream>>>(pooled, lw, lb, out);
}

// Round 6
// 468.656 us; speedup vs baseline: 2.5296x; 1.0586x over previous
//
#include <hip/hip_runtime.h>
#include <hip/hip_bf16.h>

// SymbolicGNN, CSR two-phase, v6.
// - Weights pre-packed (k_init) into MFMA-fragment order bf16: each A-frag load in
//   k_msg is ONE 16B load (was 8 scalar f32 loads + 8 cvts re-materialized per tile
//   -> round-5's VGPR_Count=64 showed compiler sank fragment loads into the loop).
// - k_msg fuses segment-reduce + fp32 atomic scatter (CSR-sorted objs => contiguous
//   runs): GEMM2 -> fp32 sMsg LDS -> per-(col,8row-chunk) run sums -> ~14M coalesced
//   wave-uniform atomics. Deletes msgb (133MB wr + 128MB rd) and k_agg x2.
// - lgkmcnt-only barriers (3/tile) keep prefetched gathers in flight.
// - grid 1280, launch_bounds(256,5): LDS 30.4KB -> 5 blocks/CU.

#define N_NODES 100000
#define NV_ELEMS (N_NODES * 64)
#define N_EDGES 1000000
#define EV_ELEMS (131075 * 64)   // VOCAB * ES
#define ES 64
#define TILE 32
#define NTILES (N_EDGES / TILE)
#define SCAN_B 1024
#define SCAN_NB ((N_NODES + SCAN_B - 1) / SCAN_B)   // 98

typedef __bf16 bf16x8 __attribute__((ext_vector_type(8)));
typedef __bf16 bf16x4 __attribute__((ext_vector_type(4)));
typedef float f32x4 __attribute__((ext_vector_type(4)));

__device__ __forceinline__ f32x4 mfma_16x16x32(bf16x8 a, bf16x8 b, f32x4 c) {
    return __builtin_amdgcn_mfma_f32_16x16x32_bf16(a, b, c, 0, 0, 0);
}

// LDS-only barrier: cross-thread deps in k_msg are all LDS (sX/sHm/sMsg/sO2);
// leaves global loads (gather prefetch) and atomics in flight.
#define BAR() asm volatile("s_waitcnt lgkmcnt(0)\n\ts_barrier" ::: "memory")

// tanh-form GELU, sign-split so exp2 arg <= 0. ~11 VALU ops, 2 transcendental.
__device__ __forceinline__ float gelu_tanh(float v) {
    float x2 = v * v;
    float u  = v * fmaf(x2, 0.0356774081f, 0.7978845608f);
    float au = fabsf(u);
    float t  = __builtin_amdgcn_exp2f(au * -2.8853900818f);  // e^{-2|u|}
    float r  = __builtin_amdgcn_rcpf(1.0f + t);
    float th = fmaf(-2.0f * t, r, 1.0f);                     // tanh(|u|)
    float s  = (v >= 0.0f) ? th : -th;
    float hv = 0.5f * v;
    return fmaf(hv, s, hv);
}

__global__ void k_init(const float* __restrict__ sym, const float* __restrict__ eemb,
                       const float* __restrict__ w1, const float* __restrict__ w2,
                       float* __restrict__ A, __bf16* __restrict__ hb,
                       __bf16* __restrict__ ebb,
                       __bf16* __restrict__ w1b, __bf16* __restrict__ w2b,
                       float* __restrict__ pooled, int* __restrict__ cnt) {
    const int gid = blockIdx.x * blockDim.x + threadIdx.x;
    const int gstride = gridDim.x * blockDim.x;
    const int nv4 = NV_ELEMS / 4;
    const float4* s4 = (const float4*)sym;
    float4* a4 = (float4*)A;
    for (int i = gid; i < nv4; i += gstride) {
        float4 v = s4[i];
        a4[i] = v;
        bf16x4 p;
        p[0] = (__bf16)v.x; p[1] = (__bf16)v.y; p[2] = (__bf16)v.z; p[3] = (__bf16)v.w;
        *(bf16x4*)(hb + (size_t)i * 4) = p;
    }
    const int ev4 = EV_ELEMS / 4;
    const float4* e4 = (const float4*)eemb;
    for (int i = gid; i < ev4; i += gstride) {
        float4 v = e4[i];
        bf16x4 p;
        p[0] = (__bf16)v.x; p[1] = (__bf16)v.y; p[2] = (__bf16)v.z; p[3] = (__bf16)v.w;
        *(bf16x4*)(ebb + (size_t)i * 4) = p;
    }
    // W1 -> fragment order: [layer][kt(6)][lg(4)][col(128)][i(8)], elem k = kt*32+lg*8+i
    for (int d = gid; d < 2 * 24576; d += gstride) {
        int layer = d / 24576, r = d - layer * 24576;
        int kt = r >> 12, lg = (r >> 10) & 3, col = (r >> 3) & 127, i = r & 7;
        w1b[d] = (__bf16)w1[layer * 24576 + (kt * 32 + lg * 8 + i) * 128 + col];
    }
    // W2 -> [layer][kt(4)][lg(4)][col(64)][i(8)]
    for (int d = gid; d < 2 * 8192; d += gstride) {
        int layer = d >> 13, r = d & 8191;
        int kt = r >> 11, lg = (r >> 9) & 3, col = (r >> 3) & 63, i = r & 7;
        w2b[d] = (__bf16)w2[layer * 8192 + (kt * 32 + lg * 8 + i) * 64 + col];
    }
    for (int i = gid; i < N_NODES; i += gstride) cnt[i] = 0;
    if (gid < ES) pooled[gid] = 0.0f;
}

__global__ void k_h2b(const float* __restrict__ A, __bf16* __restrict__ hb) {
    const int nv4 = NV_ELEMS / 4;
    const float4* a4 = (const float4*)A;
    for (int i = blockIdx.x * blockDim.x + threadIdx.x; i < nv4;
         i += gridDim.x * blockDim.x) {
        float4 v = a4[i];
        bf16x4 p;
        p[0] = (__bf16)v.x; p[1] = (__bf16)v.y; p[2] = (__bf16)v.z; p[3] = (__bf16)v.w;
        *(bf16x4*)(hb + (size_t)i * 4) = p;
    }
}

// ---------------- CSR build ----------------
__global__ void k_hist(const int* __restrict__ obj, int* __restrict__ cnt) {
    int e = blockIdx.x * blockDim.x + threadIdx.x;
    if (e < N_EDGES) atomicAdd(&cnt[obj[e]], 1);
}

__global__ __launch_bounds__(1024) void k_scanA(const int* __restrict__ cnt,
                                                int* __restrict__ off,
                                                int* __restrict__ bsum) {
    __shared__ int sp[SCAN_B];
    const int t = threadIdx.x;
    const int g = blockIdx.x * SCAN_B + t;
    int v = (g < N_NODES) ? cnt[g] : 0;
    sp[t] = v;
    __syncthreads();
#pragma unroll
    for (int d = 1; d < SCAN_B; d <<= 1) {
        int x = (t >= d) ? sp[t - d] : 0;
        __syncthreads();
        sp[t] += x;
        __syncthreads();
    }
    if (g < N_NODES) off[g] = sp[t] - v;
    if (t == SCAN_B - 1) bsum[blockIdx.x] = sp[t];
}

__global__ void k_scanB(const int* __restrict__ bsum, int* __restrict__ boff) {
    __shared__ int s[SCAN_NB];
    const int t = threadIdx.x;
    for (int i = t; i < SCAN_NB; i += 64) s[i] = bsum[i];
    __syncthreads();
    if (t == 0) {
        int run = 0;
        for (int b = 0; b < SCAN_NB; ++b) { int v = s[b]; s[b] = run; run += v; }
    }
    __syncthreads();
    for (int i = t; i < SCAN_NB; i += 64) boff[i] = s[i];
}

__global__ __launch_bounds__(1024) void k_scanC(int* __restrict__ off,
                                                const int* __restrict__ boff,
                                                int* __restrict__ cur) {
    const int g = blockIdx.x * SCAN_B + threadIdx.x;
    if (g < N_NODES) {
        int o = off[g] + boff[blockIdx.x];
        off[g] = o;
        cur[g] = o;
    }
    if (g == 0) off[N_NODES] = N_EDGES;
}

__global__ void k_fill(const int* __restrict__ subj, const int* __restrict__ pred,
                       const int* __restrict__ obj, int* __restrict__ cur,
                       int4* __restrict__ eT) {
    int e = blockIdx.x * blockDim.x + threadIdx.x;
    if (e >= N_EDGES) return;
    int o = obj[e];
    int pos = atomicAdd(&cur[o], 1);
    eT[pos] = make_int4(subj[e], pred[e], o, 0);
}

// ---------------- fused: edge MLP + in-tile segment reduce + atomic scatter ----------------
__global__ __launch_bounds__(256, 5) void k_msg(
    const int4* __restrict__ eT,
    const __bf16* __restrict__ hb, const __bf16* __restrict__ ebb,
    float* __restrict__ A,
    const __bf16* __restrict__ w1b, const float* __restrict__ b1,
    const __bf16* __restrict__ w2b, const float* __restrict__ b2) {
    __shared__ __bf16 sX[TILE][200];    // 12.8 KB
    __shared__ __bf16 sHm[TILE][136];   // 8.7 KB
    __shared__ float  sMsg[TILE][68];   // 8.7 KB (fp32 msg, conflict-min layout)
    __shared__ int    sO2[2][TILE];     // double-buffered obj ids

    const int tid = threadIdx.x;
    const int w   = tid >> 6;
    const int l   = tid & 63;
    const int lg  = l >> 4;
    const int lc  = l & 15;
    const int g16 = tid >> 4, l16 = tid & 15;
    const int row0 = g16, row1 = g16 + 16;

    // fragment base pointers (pre-packed): one 16B load per fragment
    const __bf16* w1f = w1b + (size_t)(lg * 1024 + (w * 32 + lc) * 8);  // + kt*4096 + nt*128
    const __bf16* w2f = w2b + (size_t)(lg * 512 + (w * 16 + lc) * 8);   // + kt*2048

    f32x4 b1q[2];
    b1q[0] = *(const f32x4*)(b1 + w * 32 + lg * 4);
    b1q[1] = *(const f32x4*)(b1 + w * 32 + 16 + lg * 4);
    f32x4 b2q = *(const f32x4*)(b2 + w * 16 + lg * 4);

    int tile = blockIdx.x;
    int j0   = tile * TILE;
    int pp   = 0;
    if (tile >= NTILES) return;

    int4 e0 = eT[j0 + row0];
    int4 e1 = eT[j0 + row1];
    bf16x4 rb[6];
    rb[0] = *(const bf16x4*)(hb  + (size_t)e0.x * ES + l16 * 4);
    rb[1] = *(const bf16x4*)(hb  + (size_t)e1.x * ES + l16 * 4);
    rb[2] = *(const bf16x4*)(ebb + (size_t)e0.y * ES + l16 * 4);
    rb[3] = *(const bf16x4*)(ebb + (size_t)e1.y * ES + l16 * 4);
    rb[4] = *(const bf16x4*)(hb  + (size_t)e0.z * ES + l16 * 4);
    rb[5] = *(const bf16x4*)(hb  + (size_t)e1.z * ES + l16 * 4);

    for (; tile < NTILES; tile += gridDim.x) {
        const int jn = (tile + (int)gridDim.x < NTILES) ? (tile + gridDim.x) * TILE : j0;

        // ---- stage current tile (regs -> LDS), then issue next tile's index loads ----
        *(bf16x4*)&sX[row0][      l16 * 4] = rb[0];
        *(bf16x4*)&sX[row1][      l16 * 4] = rb[1];
        *(bf16x4*)&sX[row0][ 64 + l16 * 4] = rb[2];
        *(bf16x4*)&sX[row1][ 64 + l16 * 4] = rb[3];
        *(bf16x4*)&sX[row0][128 + l16 * 4] = rb[4];
        *(bf16x4*)&sX[row1][128 + l16 * 4] = rb[5];
        if (l16 == 0) {
            sO2[pp][row0] = e0.z;
            sO2[pp][row1] = e1.z;
        }
        e0 = eT[jn + row0];
        e1 = eT[jn + row1];
        BAR();  // bar1: sX, sO2 ready

        // ---- prefetch next tile's gather rows (hides under GEMM1+GELU+GEMM2+reduce) ----
        rb[0] = *(const bf16x4*)(hb  + (size_t)e0.x * ES + l16 * 4);
        rb[1] = *(const bf16x4*)(hb  + (size_t)e1.x * ES + l16 * 4);
        rb[2] = *(const bf16x4*)(ebb + (size_t)e0.y * ES + l16 * 4);
        rb[3] = *(const bf16x4*)(ebb + (size_t)e1.y * ES + l16 * 4);
        rb[4] = *(const bf16x4*)(hb  + (size_t)e0.z * ES + l16 * 4);
        rb[5] = *(const bf16x4*)(hb  + (size_t)e1.z * ES + l16 * 4);

        // ---- GEMM1 (transposed): C[outcol][edge], fragment = one 16B load ----
        f32x4 acc1[2][2];
#pragma unroll
        for (int nt = 0; nt < 2; ++nt)
#pragma unroll
            for (int mt = 0; mt < 2; ++mt) acc1[nt][mt] = (f32x4){0.f, 0.f, 0.f, 0.f};
#pragma unroll
        for (int kt = 0; kt < 6; ++kt) {
            bf16x8 x0  = *(const bf16x8*)&sX[lc][kt * 32 + lg * 8];
            bf16x8 x1  = *(const bf16x8*)&sX[16 + lc][kt * 32 + lg * 8];
            bf16x8 wf0 = *(const bf16x8*)(w1f + kt * 4096);
            bf16x8 wf1 = *(const bf16x8*)(w1f + kt * 4096 + 128);
            acc1[0][0] = mfma_16x16x32(wf0, x0, acc1[0][0]);
            acc1[0][1] = mfma_16x16x32(wf0, x1, acc1[0][1]);
            acc1[1][0] = mfma_16x16x32(wf1, x0, acc1[1][0]);
            acc1[1][1] = mfma_16x16x32(wf1, x1, acc1[1][1]);
        }

        // ---- bias + GELU, packed b64 writes: 4 consecutive hmid cols per lane ----
#pragma unroll
        for (int nt = 0; nt < 2; ++nt)
#pragma unroll
            for (int mt = 0; mt < 2; ++mt) {
                bf16x4 hq;
#pragma unroll
                for (int r = 0; r < 4; ++r)
                    hq[r] = (__bf16)gelu_tanh(acc1[nt][mt][r] + b1q[nt][r]);
                *(bf16x4*)&sHm[mt * 16 + lc][w * 32 + nt * 16 + lg * 4] = hq;
            }
        BAR();  // bar2: sHm ready

        // ---- GEMM2 (transposed): lane holds msg[edge=lc(+16)][cols w*16+lg*4..+3] ----
        f32x4 acc2[2];
        acc2[0] = (f32x4){0.f, 0.f, 0.f, 0.f};
        acc2[1] = (f32x4){0.f, 0.f, 0.f, 0.f};
#pragma unroll
        for (int kt = 0; kt < 4; ++kt) {
            bf16x8 h0 = *(const bf16x8*)&sHm[lc][kt * 32 + lg * 8];
            bf16x8 h1 = *(const bf16x8*)&sHm[16 + lc][kt * 32 + lg * 8];
            bf16x8 wf = *(const bf16x8*)(w2f + kt * 2048);
            acc2[0] = mfma_16x16x32(wf, h0, acc2[0]);
            acc2[1] = mfma_16x16x32(wf, h1, acc2[1]);
        }
        {
            f32x4 m0 = acc2[0] + b2q;
            f32x4 m1 = acc2[1] + b2q;
            *(f32x4*)&sMsg[lc][w * 16 + lg * 4]      = m0;
            *(f32x4*)&sMsg[16 + lc][w * 16 + lg * 4] = m1;
        }
        BAR();  // bar3: sMsg ready

        // ---- in-tile segment reduce (objs sorted => contiguous runs), atomic per run ----
        // thread owns col c, rows r0..r0+7; run-break conditions are wave-uniform.
        {
            const int c  = tid & 63;
            const int r0 = (tid >> 6) * 8;
            int   curo = sO2[pp][r0];
            float run  = sMsg[r0][c];
#pragma unroll
            for (int k2 = 1; k2 < 8; ++k2) {
                int   o = sO2[pp][r0 + k2];
                float v = sMsg[r0 + k2][c];
                if (o != curo) {
                    atomicAdd(&A[(size_t)curo * ES + c], run);
                    curo = o;
                    run  = v;
                } else {
                    run += v;
                }
            }
            atomicAdd(&A[(size_t)curo * ES + c], run);
        }
        pp ^= 1;
        j0 = jn;
    }
}

__global__ void k_pool(const float* __restrict__ h, float* __restrict__ pooled) {
    __shared__ float sm[256];
    float acc = 0.f;
    for (int idx = blockIdx.x * 256 + threadIdx.x; idx < NV_ELEMS; idx += gridDim.x * 256)
        acc += h[idx];
    sm[threadIdx.x] = acc;
    __syncthreads();
    if (threadIdx.x < 64) {
        float s = sm[threadIdx.x] + sm[threadIdx.x + 64] + sm[threadIdx.x + 128] +
                  sm[threadIdx.x + 192];
        atomicAdd(&pooled[threadIdx.x], s);
    }
}

__global__ void k_final(const float* __restrict__ pooled, const float* __restrict__ w,
                        const float* __restrict__ b, float* __restrict__ out) {
    __shared__ float sp[64];
    if (threadIdx.x < 64) sp[threadIdx.x] = pooled[threadIdx.x] * (1.0f / N_NODES);
    __syncthreads();
    const int c = threadIdx.x;
    float s = b[c];
#pragma unroll
    for (int j = 0; j < 64; ++j) s += sp[j] * w[j * 256 + c];
    out[c] = s;
}

extern "C" void kernel_launch(void* const* d_in, const int* in_sizes, int n_in,
                              void* d_out, int out_size, void* d_ws, size_t ws_size,
                              hipStream_t stream) {
    const int*   subj = (const int*)d_in[0];
    const int*   pred = (const int*)d_in[1];
    const int*   obj  = (const int*)d_in[2];
    const float* sym  = (const float*)d_in[3];
    const float* eemb = (const float*)d_in[4];
    const float* w1   = (const float*)d_in[5];
    const float* b1   = (const float*)d_in[6];
    const float* w2   = (const float*)d_in[7];
    const float* b2   = (const float*)d_in[8];
    const float* lw   = (const float*)d_in[9];
    const float* lb   = (const float*)d_in[10];
    float* out = (float*)d_out;

    // ---- ws layout (~73 MB, all blocks 16B-aligned) ----
    char* p = (char*)d_ws;
    float*  A      = (float*)p;   p += (size_t)NV_ELEMS * 4;        // 25.6 MB
    __bf16* hb     = (__bf16*)p;  p += (size_t)NV_ELEMS * 2;        // 12.8 MB
    __bf16* ebb    = (__bf16*)p;  p += (size_t)EV_ELEMS * 2;        // 16.8 MB
    __bf16* w1b    = (__bf16*)p;  p += (size_t)2 * 24576 * 2;       // 98 KB
    __bf16* w2b    = (__bf16*)p;  p += (size_t)2 * 8192 * 2;        // 32 KB
    float*  pooled = (float*)p;   p += 256;
    int*    cnt    = (int*)p;     p += (size_t)N_NODES * 4;
    int*    off    = (int*)p;     p += (size_t)(N_NODES + 4) * 4;
    int*    cur    = (int*)p;     p += (size_t)N_NODES * 4;
    int4*   eT     = (int4*)p;    p += (size_t)N_EDGES * 16;        // 16 MB
    int*    bsum   = (int*)p;     p += 400;
    int*    boff   = (int*)p;     p += 400;
    (void)ws_size;

    const int EB = (N_EDGES + 255) / 256;

    k_init<<<2048, 256, 0, stream>>>(sym, eemb, w1, w2, A, hb, ebb, w1b, w2b,
                                     pooled, cnt);
    k_hist<<<EB, 256, 0, stream>>>(obj, cnt);
    k_scanA<<<SCAN_NB, SCAN_B, 0, stream>>>(cnt, off, bsum);
    k_scanB<<<1, 64, 0, stream>>>(bsum, boff);
    k_scanC<<<SCAN_NB, SCAN_B, 0, stream>>>(off, boff, cur);
    k_fill<<<EB, 256, 0, stream>>>(subj, pred, obj, cur, eT);
    // layer 0: gather hb, fused reduce-scatter into A (A pre-initialized to h0)
    k_msg<<<1280, 256, 0, stream>>>(eT, hb, ebb, A, w1b, b1, w2b, b2);
    // refresh bf16 mirror
    k_h2b<<<2048, 256, 0, stream>>>(A, hb);
    // layer 1: gather hb, scatter in-place into A
    k_msg<<<1280, 256, 0, stream>>>(eT, hb, ebb, A, w1b + 24576, b1 + 128,
                                    w2b + 8192, b2 + 64);
    // pool + head
    k_pool<<<256, 256, 0, stream>>>(A, pooled);
    k_final<<<1, 256, 0, stream>>>(pooled, lw, lb, out);
}

// Round 7
// 375.540 us; speedup vs baseline: 3.1568x; 1.2480x over previous
//
#include <hip/hip_runtime.h>
#include <hip/hip_bf16.h>

// SymbolicGNN, CSR two-phase, v7.
// Round-6 counters: VGPR_Count=48 -> compiler re-loaded all 16 weight fragments
// from global EVERY tile (~2GB L1/L2 traffic + issue slots). Fix: pin fragments
// with empty asm("+v") so remat is impossible; launch_bounds(256,4) gives the
// 128-VGPR headroom. Plus: 7-op sigmoid-form GELU (overflow-safe, no select),
// and staging re-plan (1 int4 + 3 bf16x8 loads + 3 ds_write_b128 per thread/tile,
// was 2+6 loads and 6 b64 writes). Fused run-reduce scatter kept (WRITE 53MB ok).

#define N_NODES 100000
#define NV_ELEMS (N_NODES * 64)
#define N_EDGES 1000000
#define EV_ELEMS (131075 * 64)   // VOCAB * ES
#define ES 64
#define TILE 32
#define NTILES (N_EDGES / TILE)
#define SCAN_B 1024
#define SCAN_NB ((N_NODES + SCAN_B - 1) / SCAN_B)   // 98

typedef __bf16 bf16x8 __attribute__((ext_vector_type(8)));
typedef __bf16 bf16x4 __attribute__((ext_vector_type(4)));
typedef float f32x4 __attribute__((ext_vector_type(4)));

__device__ __forceinline__ f32x4 mfma_16x16x32(bf16x8 a, bf16x8 b, f32x4 c) {
    return __builtin_amdgcn_mfma_f32_16x16x32_bf16(a, b, c, 0, 0, 0);
}

// LDS-only barrier: cross-thread deps in k_msg are all LDS (sX/sHm/sMsg/sO2);
// global loads (gather prefetch) and atomics stay in flight across it.
#define BAR() asm volatile("s_waitcnt lgkmcnt(0)\n\ts_barrier" ::: "memory")

// tanh-GELU via sigmoid identity: 0.5v(1+tanh(k(v+c v^3))) = v*sigmoid(2k(v+c v^3))
//   = v * rcp(1 + exp2(-(2.30227911 v + 0.10294538 v^3))).
// Overflow-safe: v->+inf: exp2->0 -> v;  v->-inf: exp2->inf -> rcp(inf)=0 -> 0.
// 7 VALU ops (2 transcendental), no compare/select.
__device__ __forceinline__ float gelu_fast(float v) {
    float z = v * fmaf(v * v, -0.10294538f, -2.30227911f);
    float t = __builtin_amdgcn_exp2f(z);
    return v * __builtin_amdgcn_rcpf(1.0f + t);
}

__global__ void k_init(const float* __restrict__ sym, const float* __restrict__ eemb,
                       const float* __restrict__ w1, const float* __restrict__ w2,
                       float* __restrict__ A, __bf16* __restrict__ hb,
                       __bf16* __restrict__ ebb,
                       __bf16* __restrict__ w1b, __bf16* __restrict__ w2b,
                       float* __restrict__ pooled, int* __restrict__ cnt) {
    const int gid = blockIdx.x * blockDim.x + threadIdx.x;
    const int gstride = gridDim.x * blockDim.x;
    const int nv4 = NV_ELEMS / 4;
    const float4* s4 = (const float4*)sym;
    float4* a4 = (float4*)A;
    for (int i = gid; i < nv4; i += gstride) {
        float4 v = s4[i];
        a4[i] = v;
        bf16x4 p;
        p[0] = (__bf16)v.x; p[1] = (__bf16)v.y; p[2] = (__bf16)v.z; p[3] = (__bf16)v.w;
        *(bf16x4*)(hb + (size_t)i * 4) = p;
    }
    const int ev4 = EV_ELEMS / 4;
    const float4* e4 = (const float4*)eemb;
    for (int i = gid; i < ev4; i += gstride) {
        float4 v = e4[i];
        bf16x4 p;
        p[0] = (__bf16)v.x; p[1] = (__bf16)v.y; p[2] = (__bf16)v.z; p[3] = (__bf16)v.w;
        *(bf16x4*)(ebb + (size_t)i * 4) = p;
    }
    // W1 -> fragment order: [layer][kt(6)][lg(4)][col(128)][i(8)], elem k = kt*32+lg*8+i
    for (int d = gid; d < 2 * 24576; d += gstride) {
        int layer = d / 24576, r = d - layer * 24576;
        int kt = r >> 12, lg = (r >> 10) & 3, col = (r >> 3) & 127, i = r & 7;
        w1b[d] = (__bf16)w1[layer * 24576 + (kt * 32 + lg * 8 + i) * 128 + col];
    }
    // W2 -> [layer][kt(4)][lg(4)][col(64)][i(8)]
    for (int d = gid; d < 2 * 8192; d += gstride) {
        int layer = d >> 13, r = d & 8191;
        int kt = r >> 11, lg = (r >> 9) & 3, col = (r >> 3) & 63, i = r & 7;
        w2b[d] = (__bf16)w2[layer * 8192 + (kt * 32 + lg * 8 + i) * 64 + col];
    }
    for (int i = gid; i < N_NODES; i += gstride) cnt[i] = 0;
    if (gid < ES) pooled[gid] = 0.0f;
}

__global__ void k_h2b(const float* __restrict__ A, __bf16* __restrict__ hb) {
    const int nv4 = NV_ELEMS / 4;
    const float4* a4 = (const float4*)A;
    for (int i = blockIdx.x * blockDim.x + threadIdx.x; i < nv4;
         i += gridDim.x * blockDim.x) {
        float4 v = a4[i];
        bf16x4 p;
        p[0] = (__bf16)v.x; p[1] = (__bf16)v.y; p[2] = (__bf16)v.z; p[3] = (__bf16)v.w;
        *(bf16x4*)(hb + (size_t)i * 4) = p;
    }
}

// ---------------- CSR build ----------------
__global__ void k_hist(const int* __restrict__ obj, int* __restrict__ cnt) {
    int e = blockIdx.x * blockDim.x + threadIdx.x;
    if (e < N_EDGES) atomicAdd(&cnt[obj[e]], 1);
}

__global__ __launch_bounds__(1024) void k_scanA(const int* __restrict__ cnt,
                                                int* __restrict__ off,
                                                int* __restrict__ bsum) {
    __shared__ int sp[SCAN_B];
    const int t = threadIdx.x;
    const int g = blockIdx.x * SCAN_B + t;
    int v = (g < N_NODES) ? cnt[g] : 0;
    sp[t] = v;
    __syncthreads();
#pragma unroll
    for (int d = 1; d < SCAN_B; d <<= 1) {
        int x = (t >= d) ? sp[t - d] : 0;
        __syncthreads();
        sp[t] += x;
        __syncthreads();
    }
    if (g < N_NODES) off[g] = sp[t] - v;
    if (t == SCAN_B - 1) bsum[blockIdx.x] = sp[t];
}

__global__ void k_scanB(const int* __restrict__ bsum, int* __restrict__ boff) {
    __shared__ int s[SCAN_NB];
    const int t = threadIdx.x;
    for (int i = t; i < SCAN_NB; i += 64) s[i] = bsum[i];
    __syncthreads();
    if (t == 0) {
        int run = 0;
        for (int b = 0; b < SCAN_NB; ++b) { int v = s[b]; s[b] = run; run += v; }
    }
    __syncthreads();
    for (int i = t; i < SCAN_NB; i += 64) boff[i] = s[i];
}

__global__ __launch_bounds__(1024) void k_scanC(int* __restrict__ off,
                                                const int* __restrict__ boff,
                                                int* __restrict__ cur) {
    const int g = blockIdx.x * SCAN_B + threadIdx.x;
    if (g < N_NODES) {
        int o = off[g] + boff[blockIdx.x];
        off[g] = o;
        cur[g] = o;
    }
    if (g == 0) off[N_NODES] = N_EDGES;
}

__global__ void k_fill(const int* __restrict__ subj, const int* __restrict__ pred,
                       const int* __restrict__ obj, int* __restrict__ cur,
                       int4* __restrict__ eT) {
    int e = blockIdx.x * blockDim.x + threadIdx.x;
    if (e >= N_EDGES) return;
    int o = obj[e];
    int pos = atomicAdd(&cur[o], 1);
    eT[pos] = make_int4(subj[e], pred[e], o, 0);
}

// ---------------- fused: edge MLP + in-tile segment reduce + atomic scatter ----------------
__global__ __launch_bounds__(256, 4) void k_msg(
    const int4* __restrict__ eT,
    const __bf16* __restrict__ hb, const __bf16* __restrict__ ebb,
    float* __restrict__ A,
    const __bf16* __restrict__ w1b, const float* __restrict__ b1,
    const __bf16* __restrict__ w2b, const float* __restrict__ b2) {
    __shared__ __bf16 sX[TILE][200];    // 12.8 KB
    __shared__ __bf16 sHm[TILE][136];   // 8.7 KB
    __shared__ float  sMsg[TILE][68];   // 8.7 KB
    __shared__ int    sO2[2][TILE];     // double-buffered obj ids

    const int tid = threadIdx.x;
    const int w   = tid >> 6;
    const int l   = tid & 63;
    const int lg  = l >> 4;
    const int lc  = l & 15;
    // staging plan: thread owns row r (32 rows), 16B chunk c8 (8 chunks), all 3 parts
    const int r  = tid >> 3;
    const int c8 = tid & 7;

    // ---- weight fragments: one 16B load each, PINNED so compiler can't remat ----
    const __bf16* w1f = w1b + (size_t)(lg * 1024 + (w * 32 + lc) * 8);  // + kt*4096 + nt*128
    const __bf16* w2f = w2b + (size_t)(lg * 512 + (w * 16 + lc) * 8);   // + kt*2048
    bf16x8 wb1[6][2];
#pragma unroll
    for (int kt = 0; kt < 6; ++kt)
#pragma unroll
        for (int nt = 0; nt < 2; ++nt) {
            wb1[kt][nt] = *(const bf16x8*)(w1f + kt * 4096 + nt * 128);
            asm volatile("" : "+v"(wb1[kt][nt]));   // pin: force register residency
        }
    bf16x8 wb2[4];
#pragma unroll
    for (int kt = 0; kt < 4; ++kt) {
        wb2[kt] = *(const bf16x8*)(w2f + kt * 2048);
        asm volatile("" : "+v"(wb2[kt]));
    }

    f32x4 b1q[2];
    b1q[0] = *(const f32x4*)(b1 + w * 32 + lg * 4);
    b1q[1] = *(const f32x4*)(b1 + w * 32 + 16 + lg * 4);
    f32x4 b2q = *(const f32x4*)(b2 + w * 16 + lg * 4);

    int tile = blockIdx.x;
    int j0   = tile * TILE;
    int pp   = 0;
    if (tile >= NTILES) return;

    // prologue: first tile's indices + gathers
    int4 e = eT[j0 + r];
    bf16x8 rb0 = *(const bf16x8*)(hb  + (size_t)e.x * ES + c8 * 8);
    bf16x8 rb1 = *(const bf16x8*)(ebb + (size_t)e.y * ES + c8 * 8);
    bf16x8 rb2 = *(const bf16x8*)(hb  + (size_t)e.z * ES + c8 * 8);

    for (; tile < NTILES; tile += gridDim.x) {
        const int jn = (tile + (int)gridDim.x < NTILES) ? (tile + gridDim.x) * TILE : j0;

        // ---- stage current tile (3 x ds_write_b128); issue next tile's index load ----
        *(bf16x8*)&sX[r][      c8 * 8] = rb0;
        *(bf16x8*)&sX[r][ 64 + c8 * 8] = rb1;
        *(bf16x8*)&sX[r][128 + c8 * 8] = rb2;
        if (c8 == 0) sO2[pp][r] = e.z;
        e = eT[jn + r];
        BAR();  // bar1: sX, sO2 ready

        // ---- prefetch next tile's gathers (hide under GEMM1+GELU+GEMM2+reduce) ----
        rb0 = *(const bf16x8*)(hb  + (size_t)e.x * ES + c8 * 8);
        rb1 = *(const bf16x8*)(ebb + (size_t)e.y * ES + c8 * 8);
        rb2 = *(const bf16x8*)(hb  + (size_t)e.z * ES + c8 * 8);

        // ---- GEMM1 (transposed): C[outcol][edge] ----
        f32x4 acc1[2][2];
#pragma unroll
        for (int nt = 0; nt < 2; ++nt)
#pragma unroll
            for (int mt = 0; mt < 2; ++mt) acc1[nt][mt] = (f32x4){0.f, 0.f, 0.f, 0.f};
#pragma unroll
        for (int kt = 0; kt < 6; ++kt) {
            bf16x8 x0 = *(const bf16x8*)&sX[lc][kt * 32 + lg * 8];
            bf16x8 x1 = *(const bf16x8*)&sX[16 + lc][kt * 32 + lg * 8];
            acc1[0][0] = mfma_16x16x32(wb1[kt][0], x0, acc1[0][0]);
            acc1[0][1] = mfma_16x16x32(wb1[kt][0], x1, acc1[0][1]);
            acc1[1][0] = mfma_16x16x32(wb1[kt][1], x0, acc1[1][0]);
            acc1[1][1] = mfma_16x16x32(wb1[kt][1], x1, acc1[1][1]);
        }

        // ---- bias + GELU, packed b64 writes: 4 consecutive hmid cols per lane ----
#pragma unroll
        for (int nt = 0; nt < 2; ++nt)
#pragma unroll
            for (int mt = 0; mt < 2; ++mt) {
                bf16x4 hq;
#pragma unroll
                for (int rr = 0; rr < 4; ++rr)
                    hq[rr] = (__bf16)gelu_fast(acc1[nt][mt][rr] + b1q[nt][rr]);
                *(bf16x4*)&sHm[mt * 16 + lc][w * 32 + nt * 16 + lg * 4] = hq;
            }
        BAR();  // bar2: sHm ready

        // ---- GEMM2 (transposed): lane holds msg[edge][4 consecutive cols] ----
        f32x4 acc2[2];
        acc2[0] = (f32x4){0.f, 0.f, 0.f, 0.f};
        acc2[1] = (f32x4){0.f, 0.f, 0.f, 0.f};
#pragma unroll
        for (int kt = 0; kt < 4; ++kt) {
            bf16x8 h0 = *(const bf16x8*)&sHm[lc][kt * 32 + lg * 8];
            bf16x8 h1 = *(const bf16x8*)&sHm[16 + lc][kt * 32 + lg * 8];
            acc2[0] = mfma_16x16x32(wb2[kt], h0, acc2[0]);
            acc2[1] = mfma_16x16x32(wb2[kt], h1, acc2[1]);
        }
        {
            f32x4 m0 = acc2[0] + b2q;
            f32x4 m1 = acc2[1] + b2q;
            *(f32x4*)&sMsg[lc][w * 16 + lg * 4]      = m0;
            *(f32x4*)&sMsg[16 + lc][w * 16 + lg * 4] = m1;
        }
        BAR();  // bar3: sMsg ready

        // ---- in-tile segment reduce (objs sorted => runs), one atomic per run ----
        {
            const int c  = tid & 63;
            const int r0 = (tid >> 6) * 8;
            int   curo = sO2[pp][r0];
            float run  = sMsg[r0][c];
#pragma unroll
            for (int k2 = 1; k2 < 8; ++k2) {
                int   o = sO2[pp][r0 + k2];
                float v = sMsg[r0 + k2][c];
                if (o != curo) {
                    atomicAdd(&A[(size_t)curo * ES + c], run);
                    curo = o;
                    run  = v;
                } else {
                    run += v;
                }
            }
            atomicAdd(&A[(size_t)curo * ES + c], run);
        }
        pp ^= 1;
        j0 = jn;
    }
}

__global__ void k_pool(const float* __restrict__ h, float* __restrict__ pooled) {
    __shared__ float sm[256];
    float acc = 0.f;
    for (int idx = blockIdx.x * 256 + threadIdx.x; idx < NV_ELEMS; idx += gridDim.x * 256)
        acc += h[idx];
    sm[threadIdx.x] = acc;
    __syncthreads();
    if (threadIdx.x < 64) {
        float s = sm[threadIdx.x] + sm[threadIdx.x + 64] + sm[threadIdx.x + 128] +
                  sm[threadIdx.x + 192];
        atomicAdd(&pooled[threadIdx.x], s);
    }
}

__global__ void k_final(const float* __restrict__ pooled, const float* __restrict__ w,
                        const float* __restrict__ b, float* __restrict__ out) {
    __shared__ float sp[64];
    if (threadIdx.x < 64) sp[threadIdx.x] = pooled[threadIdx.x] * (1.0f / N_NODES);
    __syncthreads();
    const int c = threadIdx.x;
    float s = b[c];
#pragma unroll
    for (int j = 0; j < 64; ++j) s += sp[j] * w[j * 256 + c];
    out[c] = s;
}

extern "C" void kernel_launch(void* const* d_in, const int* in_sizes, int n_in,
                              void* d_out, int out_size, void* d_ws, size_t ws_size,
                              hipStream_t stream) {
    const int*   subj = (const int*)d_in[0];
    const int*   pred = (const int*)d_in[1];
    const int*   obj  = (const int*)d_in[2];
    const float* sym  = (const float*)d_in[3];
    const float* eemb = (const float*)d_in[4];
    const float* w1   = (const float*)d_in[5];
    const float* b1   = (const float*)d_in[6];
    const float* w2   = (const float*)d_in[7];
    const float* b2   = (const float*)d_in[8];
    const float* lw   = (const float*)d_in[9];
    const float* lb   = (const float*)d_in[10];
    float* out = (float*)d_out;

    // ---- ws layout (~73 MB, all blocks 16B-aligned) ----
    char* p = (char*)d_ws;
    float*  A      = (float*)p;   p += (size_t)NV_ELEMS * 4;        // 25.6 MB
    __bf16* hb     = (__bf16*)p;  p += (size_t)NV_ELEMS * 2;        // 12.8 MB
    __bf16* ebb    = (__bf16*)p;  p += (size_t)EV_ELEMS * 2;        // 16.8 MB
    __bf16* w1b    = (__bf16*)p;  p += (size_t)2 * 24576 * 2;       // 98 KB
    __bf16* w2b    = (__bf16*)p;  p += (size_t)2 * 8192 * 2;        // 32 KB
    float*  pooled = (float*)p;   p += 256;
    int*    cnt    = (int*)p;     p += (size_t)N_NODES * 4;
    int*    off    = (int*)p;     p += (size_t)(N_NODES + 4) * 4;
    int*    cur    = (int*)p;     p += (size_t)N_NODES * 4;
    int4*   eT     = (int4*)p;    p += (size_t)N_EDGES * 16;        // 16 MB
    int*    bsum   = (int*)p;     p += 400;
    int*    boff   = (int*)p;     p += 400;
    (void)ws_size;

    const int EB = (N_EDGES + 255) / 256;

    k_init<<<2048, 256, 0, stream>>>(sym, eemb, w1, w2, A, hb, ebb, w1b, w2b,
                                     pooled, cnt);
    k_hist<<<EB, 256, 0, stream>>>(obj, cnt);
    k_scanA<<<SCAN_NB, SCAN_B, 0, stream>>>(cnt, off, bsum);
    k_scanB<<<1, 64, 0, stream>>>(bsum, boff);
    k_scanC<<<SCAN_NB, SCAN_B, 0, stream>>>(off, boff, cur);
    k_fill<<<EB, 256, 0, stream>>>(subj, pred, obj, cur, eT);
    // layer 0: gather hb, fused reduce-scatter into A (A pre-initialized to h0)
    k_msg<<<1024, 256, 0, stream>>>(eT, hb, ebb, A, w1b, b1, w2b, b2);
    // refresh bf16 mirror
    k_h2b<<<2048, 256, 0, stream>>>(A, hb);
    // layer 1: gather hb, scatter in-place into A
    k_msg<<<1024, 256, 0, stream>>>(eT, hb, ebb, A, w1b + 24576, b1 + 128,
                                    w2b + 8192, b2 + 64);
    // pool + head
    k_pool<<<256, 256, 0, stream>>>(A, pooled);
    k_final<<<1, 256, 0, stream>>>(pooled, lw, lb, out);
}

// Round 8
// 361.560 us; speedup vs baseline: 3.2789x; 1.0387x over previous
//
#include <hip/hip_runtime.h>
#include <hip/hip_bf16.h>

// SymbolicGNN, CSR two-phase, v8.
// Round-7 counters: k_msg FETCH 126MB vs 46MB working set -> gather tables thrash
// per-XCD L2 (round-robin block->XCD means every XCD touches the whole obj range).
// Fix: XCD-chunked contiguous tile assignment. Block bid processes contiguous chunk
// (bid&7)*128 + (bid>>3); the 128 blocks resident on XCD x (=bid%8) cover one
// contiguous 1/8 of the CSR-sorted edges -> obj span 3.2MB hb + 3.2MB A fits the
// XCD's 4MB L2 (obj gathers + atomic RMW become L2-local; subj/pred stay L3).
// Also: float4 k_pool. Everything else identical to v7 (pinned weight fragments,
// 7-op sigmoid GELU, fused run-reduce scatter, lgkmcnt-only barriers).

#define N_NODES 100000
#define NV_ELEMS (N_NODES * 64)
#define N_EDGES 1000000
#define EV_ELEMS (131075 * 64)   // VOCAB * ES
#define ES 64
#define TILE 32
#define NTILES (N_EDGES / TILE)
#define SCAN_B 1024
#define SCAN_NB ((N_NODES + SCAN_B - 1) / SCAN_B)   // 98

typedef __bf16 bf16x8 __attribute__((ext_vector_type(8)));
typedef __bf16 bf16x4 __attribute__((ext_vector_type(4)));
typedef float f32x4 __attribute__((ext_vector_type(4)));

__device__ __forceinline__ f32x4 mfma_16x16x32(bf16x8 a, bf16x8 b, f32x4 c) {
    return __builtin_amdgcn_mfma_f32_16x16x32_bf16(a, b, c, 0, 0, 0);
}

// LDS-only barrier: cross-thread deps in k_msg are all LDS (sX/sHm/sMsg/sO2);
// global loads (gather prefetch) and atomics stay in flight across it.
#define BAR() asm volatile("s_waitcnt lgkmcnt(0)\n\ts_barrier" ::: "memory")

// tanh-GELU via sigmoid identity: v * rcp(1 + exp2(-(2.30227911 v + 0.10294538 v^3))).
// Overflow-safe both directions. 7 VALU ops (2 transcendental), no compare/select.
__device__ __forceinline__ float gelu_fast(float v) {
    float z = v * fmaf(v * v, -0.10294538f, -2.30227911f);
    float t = __builtin_amdgcn_exp2f(z);
    return v * __builtin_amdgcn_rcpf(1.0f + t);
}

__global__ void k_init(const float* __restrict__ sym, const float* __restrict__ eemb,
                       const float* __restrict__ w1, const float* __restrict__ w2,
                       float* __restrict__ A, __bf16* __restrict__ hb,
                       __bf16* __restrict__ ebb,
                       __bf16* __restrict__ w1b, __bf16* __restrict__ w2b,
                       float* __restrict__ pooled, int* __restrict__ cnt) {
    const int gid = blockIdx.x * blockDim.x + threadIdx.x;
    const int gstride = gridDim.x * blockDim.x;
    const int nv4 = NV_ELEMS / 4;
    const float4* s4 = (const float4*)sym;
    float4* a4 = (float4*)A;
    for (int i = gid; i < nv4; i += gstride) {
        float4 v = s4[i];
        a4[i] = v;
        bf16x4 p;
        p[0] = (__bf16)v.x; p[1] = (__bf16)v.y; p[2] = (__bf16)v.z; p[3] = (__bf16)v.w;
        *(bf16x4*)(hb + (size_t)i * 4) = p;
    }
    const int ev4 = EV_ELEMS / 4;
    const float4* e4 = (const float4*)eemb;
    for (int i = gid; i < ev4; i += gstride) {
        float4 v = e4[i];
        bf16x4 p;
        p[0] = (__bf16)v.x; p[1] = (__bf16)v.y; p[2] = (__bf16)v.z; p[3] = (__bf16)v.w;
        *(bf16x4*)(ebb + (size_t)i * 4) = p;
    }
    // W1 -> fragment order: [layer][kt(6)][lg(4)][col(128)][i(8)], elem k = kt*32+lg*8+i
    for (int d = gid; d < 2 * 24576; d += gstride) {
        int layer = d / 24576, r = d - layer * 24576;
        int kt = r >> 12, lg = (r >> 10) & 3, col = (r >> 3) & 127, i = r & 7;
        w1b[d] = (__bf16)w1[layer * 24576 + (kt * 32 + lg * 8 + i) * 128 + col];
    }
    // W2 -> [layer][kt(4)][lg(4)][col(64)][i(8)]
    for (int d = gid; d < 2 * 8192; d += gstride) {
        int layer = d >> 13, r = d & 8191;
        int kt = r >> 11, lg = (r >> 9) & 3, col = (r >> 3) & 63, i = r & 7;
        w2b[d] = (__bf16)w2[layer * 8192 + (kt * 32 + lg * 8 + i) * 64 + col];
    }
    for (int i = gid; i < N_NODES; i += gstride) cnt[i] = 0;
    if (gid < ES) pooled[gid] = 0.0f;
}

__global__ void k_h2b(const float* __restrict__ A, __bf16* __restrict__ hb) {
    const int nv4 = NV_ELEMS / 4;
    const float4* a4 = (const float4*)A;
    for (int i = blockIdx.x * blockDim.x + threadIdx.x; i < nv4;
         i += gridDim.x * blockDim.x) {
        float4 v = a4[i];
        bf16x4 p;
        p[0] = (__bf16)v.x; p[1] = (__bf16)v.y; p[2] = (__bf16)v.z; p[3] = (__bf16)v.w;
        *(bf16x4*)(hb + (size_t)i * 4) = p;
    }
}

// ---------------- CSR build ----------------
__global__ void k_hist(const int* __restrict__ obj, int* __restrict__ cnt) {
    int e = blockIdx.x * blockDim.x + threadIdx.x;
    if (e < N_EDGES) atomicAdd(&cnt[obj[e]], 1);
}

__global__ __launch_bounds__(1024) void k_scanA(const int* __restrict__ cnt,
                                                int* __restrict__ off,
                                                int* __restrict__ bsum) {
    __shared__ int sp[SCAN_B];
    const int t = threadIdx.x;
    const int g = blockIdx.x * SCAN_B + t;
    int v = (g < N_NODES) ? cnt[g] : 0;
    sp[t] = v;
    __syncthreads();
#pragma unroll
    for (int d = 1; d < SCAN_B; d <<= 1) {
        int x = (t >= d) ? sp[t - d] : 0;
        __syncthreads();
        sp[t] += x;
        __syncthreads();
    }
    if (g < N_NODES) off[g] = sp[t] - v;
    if (t == SCAN_B - 1) bsum[blockIdx.x] = sp[t];
}

__global__ void k_scanB(const int* __restrict__ bsum, int* __restrict__ boff) {
    __shared__ int s[SCAN_NB];
    const int t = threadIdx.x;
    for (int i = t; i < SCAN_NB; i += 64) s[i] = bsum[i];
    __syncthreads();
    if (t == 0) {
        int run = 0;
        for (int b = 0; b < SCAN_NB; ++b) { int v = s[b]; s[b] = run; run += v; }
    }
    __syncthreads();
    for (int i = t; i < SCAN_NB; i += 64) boff[i] = s[i];
}

__global__ __launch_bounds__(1024) void k_scanC(int* __restrict__ off,
                                                const int* __restrict__ boff,
                                                int* __restrict__ cur) {
    const int g = blockIdx.x * SCAN_B + threadIdx.x;
    if (g < N_NODES) {
        int o = off[g] + boff[blockIdx.x];
        off[g] = o;
        cur[g] = o;
    }
    if (g == 0) off[N_NODES] = N_EDGES;
}

__global__ void k_fill(const int* __restrict__ subj, const int* __restrict__ pred,
                       const int* __restrict__ obj, int* __restrict__ cur,
                       int4* __restrict__ eT) {
    int e = blockIdx.x * blockDim.x + threadIdx.x;
    if (e >= N_EDGES) return;
    int o = obj[e];
    int pos = atomicAdd(&cur[o], 1);
    eT[pos] = make_int4(subj[e], pred[e], o, 0);
}

// ---------------- fused: edge MLP + in-tile segment reduce + atomic scatter ----------------
__global__ __launch_bounds__(256, 4) void k_msg(
    const int4* __restrict__ eT,
    const __bf16* __restrict__ hb, const __bf16* __restrict__ ebb,
    float* __restrict__ A,
    const __bf16* __restrict__ w1b, const float* __restrict__ b1,
    const __bf16* __restrict__ w2b, const float* __restrict__ b2) {
    __shared__ __bf16 sX[TILE][200];    // 12.8 KB
    __shared__ __bf16 sHm[TILE][136];   // 8.7 KB
    __shared__ float  sMsg[TILE][68];   // 8.7 KB
    __shared__ int    sO2[2][TILE];     // double-buffered obj ids

    const int tid = threadIdx.x;
    const int w   = tid >> 6;
    const int l   = tid & 63;
    const int lg  = l >> 4;
    const int lc  = l & 15;
    // staging plan: thread owns row r (32 rows), 16B chunk c8 (8 chunks), all 3 parts
    const int r  = tid >> 3;
    const int c8 = tid & 7;

    // ---- weight fragments: one 16B load each, PINNED so compiler can't remat ----
    const __bf16* w1f = w1b + (size_t)(lg * 1024 + (w * 32 + lc) * 8);  // + kt*4096 + nt*128
    const __bf16* w2f = w2b + (size_t)(lg * 512 + (w * 16 + lc) * 8);   // + kt*2048
    bf16x8 wb1[6][2];
#pragma unroll
    for (int kt = 0; kt < 6; ++kt)
#pragma unroll
        for (int nt = 0; nt < 2; ++nt) {
            wb1[kt][nt] = *(const bf16x8*)(w1f + kt * 4096 + nt * 128);
            asm volatile("" : "+v"(wb1[kt][nt]));   // pin: force register residency
        }
    bf16x8 wb2[4];
#pragma unroll
    for (int kt = 0; kt < 4; ++kt) {
        wb2[kt] = *(const bf16x8*)(w2f + kt * 2048);
        asm volatile("" : "+v"(wb2[kt]));
    }

    f32x4 b1q[2];
    b1q[0] = *(const f32x4*)(b1 + w * 32 + lg * 4);
    b1q[1] = *(const f32x4*)(b1 + w * 32 + 16 + lg * 4);
    f32x4 b2q = *(const f32x4*)(b2 + w * 16 + lg * 4);

    // ---- XCD-chunked contiguous tile range ----
    // blocks with bid%8==x (all on XCD x, round-robin dispatch) take chunks
    // [x*128, (x+1)*128) -> one contiguous 1/8 of the CSR-sorted edge list per XCD.
    const int chunk = ((blockIdx.x & 7) << 7) + (blockIdx.x >> 3);
    int       tile  = (int)(((long long)chunk * NTILES) >> 10);
    const int tend  = (int)(((long long)(chunk + 1) * NTILES) >> 10);
    if (tile >= tend) return;

    int j0 = tile * TILE;
    int pp = 0;

    // prologue: first tile's indices + gathers
    int4 e = eT[j0 + r];
    bf16x8 rb0 = *(const bf16x8*)(hb  + (size_t)e.x * ES + c8 * 8);
    bf16x8 rb1 = *(const bf16x8*)(ebb + (size_t)e.y * ES + c8 * 8);
    bf16x8 rb2 = *(const bf16x8*)(hb  + (size_t)e.z * ES + c8 * 8);

    for (; tile < tend; ++tile) {
        const int jn = (tile + 1 < tend) ? (tile + 1) * TILE : j0;

        // ---- stage current tile (3 x ds_write_b128); issue next tile's index load ----
        *(bf16x8*)&sX[r][      c8 * 8] = rb0;
        *(bf16x8*)&sX[r][ 64 + c8 * 8] = rb1;
        *(bf16x8*)&sX[r][128 + c8 * 8] = rb2;
        if (c8 == 0) sO2[pp][r] = e.z;
        e = eT[jn + r];
        BAR();  // bar1: sX, sO2 ready

        // ---- prefetch next tile's gathers (hide under GEMM1+GELU+GEMM2+reduce) ----
        rb0 = *(const bf16x8*)(hb  + (size_t)e.x * ES + c8 * 8);
        rb1 = *(const bf16x8*)(ebb + (size_t)e.y * ES + c8 * 8);
        rb2 = *(const bf16x8*)(hb  + (size_t)e.z * ES + c8 * 8);

        // ---- GEMM1 (transposed): C[outcol][edge] ----
        f32x4 acc1[2][2];
#pragma unroll
        for (int nt = 0; nt < 2; ++nt)
#pragma unroll
            for (int mt = 0; mt < 2; ++mt) acc1[nt][mt] = (f32x4){0.f, 0.f, 0.f, 0.f};
#pragma unroll
        for (int kt = 0; kt < 6; ++kt) {
            bf16x8 x0 = *(const bf16x8*)&sX[lc][kt * 32 + lg * 8];
            bf16x8 x1 = *(const bf16x8*)&sX[16 + lc][kt * 32 + lg * 8];
            acc1[0][0] = mfma_16x16x32(wb1[kt][0], x0, acc1[0][0]);
            acc1[0][1] = mfma_16x16x32(wb1[kt][0], x1, acc1[0][1]);
            acc1[1][0] = mfma_16x16x32(wb1[kt][1], x0, acc1[1][0]);
            acc1[1][1] = mfma_16x16x32(wb1[kt][1], x1, acc1[1][1]);
        }

        // ---- bias + GELU, packed b64 writes: 4 consecutive hmid cols per lane ----
#pragma unroll
        for (int nt = 0; nt < 2; ++nt)
#pragma unroll
            for (int mt = 0; mt < 2; ++mt) {
                bf16x4 hq;
#pragma unroll
                for (int rr = 0; rr < 4; ++rr)
                    hq[rr] = (__bf16)gelu_fast(acc1[nt][mt][rr] + b1q[nt][rr]);
                *(bf16x4*)&sHm[mt * 16 + lc][w * 32 + nt * 16 + lg * 4] = hq;
            }
        BAR();  // bar2: sHm ready

        // ---- GEMM2 (transposed): lane holds msg[edge][4 consecutive cols] ----
        f32x4 acc2[2];
        acc2[0] = (f32x4){0.f, 0.f, 0.f, 0.f};
        acc2[1] = (f32x4){0.f, 0.f, 0.f, 0.f};
#pragma unroll
        for (int kt = 0; kt < 4; ++kt) {
            bf16x8 h0 = *(const bf16x8*)&sHm[lc][kt * 32 + lg * 8];
            bf16x8 h1 = *(const bf16x8*)&sHm[16 + lc][kt * 32 + lg * 8];
            acc2[0] = mfma_16x16x32(wb2[kt], h0, acc2[0]);
            acc2[1] = mfma_16x16x32(wb2[kt], h1, acc2[1]);
        }
        {
            f32x4 m0 = acc2[0] + b2q;
            f32x4 m1 = acc2[1] + b2q;
            *(f32x4*)&sMsg[lc][w * 16 + lg * 4]      = m0;
            *(f32x4*)&sMsg[16 + lc][w * 16 + lg * 4] = m1;
        }
        BAR();  // bar3: sMsg ready

        // ---- in-tile segment reduce (objs sorted => runs), one atomic per run ----
        {
            const int c  = tid & 63;
            const int r0 = (tid >> 6) * 8;
            int   curo = sO2[pp][r0];
            float run  = sMsg[r0][c];
#pragma unroll
            for (int k2 = 1; k2 < 8; ++k2) {
                int   o = sO2[pp][r0 + k2];
                float v = sMsg[r0 + k2][c];
                if (o != curo) {
                    atomicAdd(&A[(size_t)curo * ES + c], run);
                    curo = o;
                    run  = v;
                } else {
                    run += v;
                }
            }
            atomicAdd(&A[(size_t)curo * ES + c], run);
        }
        pp ^= 1;
        j0 = jn;
    }
}

__global__ void k_pool(const float* __restrict__ h, float* __restrict__ pooled) {
    __shared__ float sm[256 * 4];
    const int nv4 = NV_ELEMS / 4;
    f32x4 acc = (f32x4){0.f, 0.f, 0.f, 0.f};
    // col-quad of element i4 is (i4 & 15); per-thread quad is constant since the
    // grid stride (256 blocks * 256 threads) is a multiple of 16.
    for (int i4 = blockIdx.x * 256 + threadIdx.x; i4 < nv4; i4 += gridDim.x * 256)
        acc += *(const f32x4*)(h + (size_t)i4 * 4);
    *(f32x4*)&sm[threadIdx.x * 4] = acc;
    __syncthreads();
    if (threadIdx.x < 64) {
        const int q = threadIdx.x >> 2;   // col quad 0..15
        const int j = threadIdx.x & 3;    // element within quad
        float s = 0.f;
#pragma unroll
        for (int m = 0; m < 16; ++m) s += sm[(m * 16 + q) * 4 + j];
        atomicAdd(&pooled[q * 4 + j], s);
    }
}

__global__ void k_final(const float* __restrict__ pooled, const float* __restrict__ w,
                        const float* __restrict__ b, float* __restrict__ out) {
    __shared__ float sp[64];
    if (threadIdx.x < 64) sp[threadIdx.x] = pooled[threadIdx.x] * (1.0f / N_NODES);
    __syncthreads();
    const int c = threadIdx.x;
    float s = b[c];
#pragma unroll
    for (int j = 0; j < 64; ++j) s += sp[j] * w[j * 256 + c];
    out[c] = s;
}

extern "C" void kernel_launch(void* const* d_in, const int* in_sizes, int n_in,
                              void* d_out, int out_size, void* d_ws, size_t ws_size,
                              hipStream_t stream) {
    const int*   subj = (const int*)d_in[0];
    const int*   pred = (const int*)d_in[1];
    const int*   obj  = (const int*)d_in[2];
    const float* sym  = (const float*)d_in[3];
    const float* eemb = (const float*)d_in[4];
    const float* w1   = (const float*)d_in[5];
    const float* b1   = (const float*)d_in[6];
    const float* w2   = (const float*)d_in[7];
    const float* b2   = (const float*)d_in[8];
    const float* lw   = (const float*)d_in[9];
    const float* lb   = (const float*)d_in[10];
    float* out = (float*)d_out;

    // ---- ws layout (~73 MB, all blocks 16B-aligned) ----
    char* p = (char*)d_ws;
    float*  A      = (float*)p;   p += (size_t)NV_ELEMS * 4;        // 25.6 MB
    __bf16* hb     = (__bf16*)p;  p += (size_t)NV_ELEMS * 2;        // 12.8 MB
    __bf16* ebb    = (__bf16*)p;  p += (size_t)EV_ELEMS * 2;        // 16.8 MB
    __bf16* w1b    = (__bf16*)p;  p += (size_t)2 * 24576 * 2;       // 98 KB
    __bf16* w2b    = (__bf16*)p;  p += (size_t)2 * 8192 * 2;        // 32 KB
    float*  pooled = (float*)p;   p += 256;
    int*    cnt    = (int*)p;     p += (size_t)N_NODES * 4;
    int*    off    = (int*)p;     p += (size_t)(N_NODES + 4) * 4;
    int*    cur    = (int*)p;     p += (size_t)N_NODES * 4;
    int4*   eT     = (int4*)p;    p += (size_t)N_EDGES * 16;        // 16 MB
    int*    bsum   = (int*)p;     p += 400;
    int*    boff   = (int*)p;     p += 400;
    (void)ws_size;

    const int EB = (N_EDGES + 255) / 256;

    k_init<<<2048, 256, 0, stream>>>(sym, eemb, w1, w2, A, hb, ebb, w1b, w2b,
                                     pooled, cnt);
    k_hist<<<EB, 256, 0, stream>>>(obj, cnt);
    k_scanA<<<SCAN_NB, SCAN_B, 0, stream>>>(cnt, off, bsum);
    k_scanB<<<1, 64, 0, stream>>>(bsum, boff);
    k_scanC<<<SCAN_NB, SCAN_B, 0, stream>>>(off, boff, cur);
    k_fill<<<EB, 256, 0, stream>>>(subj, pred, obj, cur, eT);
    // layer 0: gather hb, fused reduce-scatter into A (A pre-initialized to h0)
    k_msg<<<1024, 256, 0, stream>>>(eT, hb, ebb, A, w1b, b1, w2b, b2);
    // refresh bf16 mirror
    k_h2b<<<2048, 256, 0, stream>>>(A, hb);
    // layer 1: gather hb, scatter in-place into A
    k_msg<<<1024, 256, 0, stream>>>(eT, hb, ebb, A, w1b + 24576, b1 + 128,
                                    w2b + 8192, b2 + 64);
    // pool + head
    k_pool<<<256, 256, 0, stream>>>(A, pooled);
    k_final<<<1, 256, 0, stream>>>(pooled, lw, lb, out);
}